// Round 4
// baseline (533.270 us; speedup 1.0000x reference)
//
#include <hip/hip_runtime.h>
#include <hip/hip_bf16.h>

#define N_NODES 50000
#define N_EDGES 800000
#define N_GRAPHS 64

typedef __attribute__((ext_vector_type(4))) short s4v;
typedef __attribute__((ext_vector_type(8))) short s8v;
typedef __attribute__((ext_vector_type(16))) float f16v;

struct HL { short hi, lo; };

// round-to-nearest-even split of fp32 into bf16 hi + bf16 lo
__device__ inline HL bsplit(float f) {
    HL r;
    unsigned u = __float_as_uint(f);
    unsigned rh = (u + 0x7FFFu + ((u >> 16) & 1u)) >> 16;
    r.hi = (short)rh;
    float fh = __uint_as_float(rh << 16);
    float fl = f - fh;
    unsigned u2 = __float_as_uint(fl);
    unsigned rl = (u2 + 0x7FFFu + ((u2 >> 16) & 1u)) >> 16;
    r.lo = (short)rl;
    return r;
}

// ---------------- degree / normalization / CSR ----------------

__global__ void k_hist(const int* __restrict__ ei, int* __restrict__ cnt, int E) {
    int e = blockIdx.x * 256 + threadIdx.x;
    if (e < E) atomicAdd(&cnt[ei[E + e]], 1);
}

__global__ void k_dinv(const int* __restrict__ cnt, float* __restrict__ dinv, int n) {
    int i = blockIdx.x * 256 + threadIdx.x;
    if (i < n) dinv[i] = rsqrtf((float)(cnt[i] + 1));
}

__global__ __launch_bounds__(512) void k_scan_a(const int* __restrict__ cnt,
                                                int* __restrict__ rowptr,
                                                int* __restrict__ bsum, int n) {
    __shared__ int s[512];
    int t = threadIdx.x;
    int i = blockIdx.x * 512 + t;
    int v = (i < n) ? cnt[i] : 0;
    s[t] = v;
    __syncthreads();
    for (int d = 1; d < 512; d <<= 1) {
        int x = (t >= d) ? s[t - d] : 0;
        __syncthreads();
        s[t] += x;
        __syncthreads();
    }
    if (i < n) rowptr[i] = s[t] - v;
    if (t == 511) bsum[blockIdx.x] = s[511];
}

__global__ __launch_bounds__(128) void k_scan_b(int* __restrict__ bsum, int nb) {
    __shared__ int s[128];
    int t = threadIdx.x;
    int v = (t < nb) ? bsum[t] : 0;
    s[t] = v;
    __syncthreads();
    for (int d = 1; d < 128; d <<= 1) {
        int x = (t >= d) ? s[t - d] : 0;
        __syncthreads();
        s[t] += x;
        __syncthreads();
    }
    if (t < nb) bsum[t] = s[t] - v;
}

__global__ __launch_bounds__(512) void k_scan_c(int* __restrict__ rowptr,
                                                const int* __restrict__ bsum,
                                                int n, int E) {
    int i = blockIdx.x * 512 + threadIdx.x;
    if (i < n) rowptr[i] += bsum[blockIdx.x];
    if (i == 0) rowptr[n] = E;
}

__global__ void k_fill_csr(const int* __restrict__ ei, const int* __restrict__ rowptr,
                           int* __restrict__ fill, int* __restrict__ colA, int E) {
    int e = blockIdx.x * 256 + threadIdx.x;
    if (e >= E) return;
    int s = ei[e], d = ei[E + e];
    int pos = rowptr[d] + atomicAdd(&fill[d], 1);
    colA[pos] = s;
}

// ---------------- weight split+transpose precompute ----------------
// Produces WT_hi/WT_lo [cols][k=128] bf16 for W0,W1,W2,fc1_top (128x128) and fc2 (128x32).
__global__ void k_wsplit(const float* __restrict__ W0, const float* __restrict__ W1,
                         const float* __restrict__ W2, const float* __restrict__ fc1,
                         const float* __restrict__ fc2w,
                         short* __restrict__ WH, short* __restrict__ WL) {
    int i = blockIdx.x * 256 + threadIdx.x;
    if (i >= 69632) return;
    float val;
    int dst;
    if (i < 65536) {
        int mat = i >> 14, off = i & 16383;
        int k = off >> 7, n = off & 127;
        const float* src = (mat == 0) ? W0 : (mat == 1) ? W1 : (mat == 2) ? W2 : fc1;
        val = src[k * 128 + n];
        dst = mat * 16384 + n * 128 + k;
    } else {
        int off = i - 65536;
        int k = off >> 5, n = off & 31;
        val = fc2w[k * 32 + n];
        dst = 65536 + n * 128 + k;
    }
    HL r = bsplit(val);
    WH[dst] = r.hi;
    WL[dst] = r.lo;
}

// ---------------- question path (k-split, 256 threads) ----------------
__global__ __launch_bounds__(256) void k_qq(const float* __restrict__ qe,
                                            const float* __restrict__ fc0w,
                                            const float* __restrict__ fc0b,
                                            const float* __restrict__ fc1bot,
                                            const float* __restrict__ fc1b,
                                            float* __restrict__ qq) {
    int g = blockIdx.x, tid = threadIdx.x;
    __shared__ float qs[768];
    __shared__ float red[256];
    __shared__ float ql[128];
    for (int i = tid; i < 768; i += 256) qs[i] = qe[g * 768 + i];
    __syncthreads();
    int j = tid & 127, half = tid >> 7;
    int kb = half * 384;
    float a0 = 0, a1 = 0, a2 = 0, a3 = 0;
    for (int k = 0; k < 384; k += 4) {
        a0 += qs[kb + k + 0] * fc0w[(kb + k + 0) * 128 + j];
        a1 += qs[kb + k + 1] * fc0w[(kb + k + 1) * 128 + j];
        a2 += qs[kb + k + 2] * fc0w[(kb + k + 2) * 128 + j];
        a3 += qs[kb + k + 3] * fc0w[(kb + k + 3) * 128 + j];
    }
    red[tid] = (a0 + a1) + (a2 + a3);
    __syncthreads();
    if (tid < 128) ql[tid] = fmaxf(red[tid] + red[tid + 128] + fc0b[tid], 0.f);
    __syncthreads();
    kb = half * 64;
    float b0 = 0, b1 = 0;
    for (int k = 0; k < 64; k += 2) {
        b0 += ql[kb + k + 0] * fc1bot[(kb + k + 0) * 128 + j];
        b1 += ql[kb + k + 1] * fc1bot[(kb + k + 1) * 128 + j];
    }
    red[tid] = b0 + b1;
    __syncthreads();
    if (tid < 128) qq[g * 128 + tid] = red[tid] + red[tid + 128] + fc1b[tid];
}

// ---------------- CSR gather (prescaled h; pure load+add per edge) ----------------
// in: Hs = h * dinv[row].  out[node] = relu((sum_src Hs[src] + Hs[node]) * dinv[node] + b)
__global__ __launch_bounds__(256) void k_gather(const float* __restrict__ Hs,
                                                const int* __restrict__ rowptr,
                                                const int* __restrict__ colA,
                                                const float* __restrict__ dinv,
                                                const float* __restrict__ bias,
                                                float* __restrict__ outp, int n) {
    int node = __builtin_amdgcn_readfirstlane(blockIdx.x * 4 + (threadIdx.x >> 6));
    if (node >= n) return;
    int lane = threadIdx.x & 63;
    int e0 = rowptr[node], e1 = rowptr[node + 1];
    const float2* base = (const float2*)Hs;   // row stride 64 float2
    float ax = 0.f, ay = 0.f;
    int e = e0;
    for (; e + 8 <= e1; e += 8) {
        int s0 = colA[e], s1 = colA[e + 1], s2 = colA[e + 2], s3 = colA[e + 3];
        int s4 = colA[e + 4], s5 = colA[e + 5], s6 = colA[e + 6], s7 = colA[e + 7];
        float2 v0 = base[(size_t)s0 * 64 + lane];
        float2 v1 = base[(size_t)s1 * 64 + lane];
        float2 v2 = base[(size_t)s2 * 64 + lane];
        float2 v3 = base[(size_t)s3 * 64 + lane];
        float2 v4 = base[(size_t)s4 * 64 + lane];
        float2 v5 = base[(size_t)s5 * 64 + lane];
        float2 v6 = base[(size_t)s6 * 64 + lane];
        float2 v7 = base[(size_t)s7 * 64 + lane];
        ax += ((v0.x + v1.x) + (v2.x + v3.x)) + ((v4.x + v5.x) + (v6.x + v7.x));
        ay += ((v0.y + v1.y) + (v2.y + v3.y)) + ((v4.y + v5.y) + (v6.y + v7.y));
    }
    for (; e < e1; ++e) {
        float2 v = base[(size_t)colA[e] * 64 + lane];
        ax += v.x;
        ay += v.y;
    }
    float di = dinv[node];
    float2 hv = base[(size_t)node * 64 + lane];
    float2 bb = ((const float2*)bias)[lane];
    float2 o;
    o.x = fmaxf((ax + hv.x) * di + bb.x, 0.f);
    o.y = fmaxf((ay + hv.y) * di + bb.y, 0.f);
    ((float2*)(outp + (size_t)node * 128))[lane] = o;
}

// ---------------- 3xBF16-split MFMA GEMM: [N,128]@[128,128] ----------------
// block = 128 thr (2 waves), tile 32 rows x 64 cols; wave w -> cols w*32..w*32+32.
// MODE 0: out = (A@W) * dinv[row]     MODE 1: out = relu(A@W + qq[batch[row]])
#define LSTR 136   // LDS row stride in shorts: 272B, 16B-aligned, conflict-free b128
template <int MODE>
__global__ __launch_bounds__(128) void gemm_mf(const float* __restrict__ A,
                                               const short* __restrict__ WTh,
                                               const short* __restrict__ WTl,
                                               const float* __restrict__ dinv,
                                               const float* __restrict__ qq,
                                               const int* __restrict__ batch,
                                               float* __restrict__ out, int nrows) {
    __shared__ short Ah[32 * LSTR], Al[32 * LSTR];
    __shared__ short Wh[64 * LSTR], Wl[64 * LSTR];
    const int tid = threadIdx.x;
    const int row0 = blockIdx.x * 32;
    const int col0 = blockIdx.y * 64;

    #pragma unroll
    for (int i = 0; i < 8; ++i) {            // A: 32 rows x 32 float4
        int u = i * 128 + tid;
        int r = u >> 5, c4 = u & 31;
        int gr = row0 + r;
        float4 v = make_float4(0.f, 0.f, 0.f, 0.f);
        if (gr < nrows) v = ((const float4*)A)[(size_t)gr * 32 + c4];
        HL px = bsplit(v.x), py = bsplit(v.y), pz = bsplit(v.z), pw = bsplit(v.w);
        s4v h4 = {px.hi, py.hi, pz.hi, pw.hi};
        s4v l4 = {px.lo, py.lo, pz.lo, pw.lo};
        *(s4v*)&Ah[r * LSTR + c4 * 4] = h4;
        *(s4v*)&Al[r * LSTR + c4 * 4] = l4;
    }
    #pragma unroll
    for (int i = 0; i < 8; ++i) {            // W: 64 cols x 16 short8
        int u = i * 128 + tid;
        int c = u >> 4, j = u & 15;
        *(s8v*)&Wh[c * LSTR + j * 8] = *(const s8v*)&WTh[(size_t)(col0 + c) * 128 + j * 8];
        *(s8v*)&Wl[c * LSTR + j * 8] = *(const s8v*)&WTl[(size_t)(col0 + c) * 128 + j * 8];
    }
    __syncthreads();

    const int wv = tid >> 6, lane = tid & 63;
    const int m = lane & 31, half = lane >> 5;
    const int colb = wv * 32;
    f16v acc = {0.f};
    #pragma unroll
    for (int ks = 0; ks < 8; ++ks) {
        int ko = ks * 16 + half * 8;
        s8v ah = *(const s8v*)&Ah[m * LSTR + ko];
        s8v al = *(const s8v*)&Al[m * LSTR + ko];
        s8v bh = *(const s8v*)&Wh[(colb + m) * LSTR + ko];
        s8v bl = *(const s8v*)&Wl[(colb + m) * LSTR + ko];
        acc = __builtin_amdgcn_mfma_f32_32x32x16_bf16(ah, bh, acc, 0, 0, 0);
        acc = __builtin_amdgcn_mfma_f32_32x32x16_bf16(ah, bl, acc, 0, 0, 0);
        acc = __builtin_amdgcn_mfma_f32_32x32x16_bf16(al, bh, acc, 0, 0, 0);
    }

    #pragma unroll
    for (int reg = 0; reg < 16; ++reg) {
        int rl = (reg & 3) + 8 * (reg >> 2) + 4 * half;
        int gr = row0 + rl;
        if (gr >= nrows) continue;
        int gc = col0 + colb + m;
        float v = acc[reg];
        if (MODE == 0) {
            v *= dinv[gr];
        } else {
            v = fmaxf(v + qq[(size_t)batch[gr] * 128 + gc], 0.f);
        }
        out[(size_t)gr * 128 + gc] = v;
    }
}

// ---------------- fc2: [N,128]@[128,32] + b (3xBF16 MFMA) ----------------
__global__ __launch_bounds__(128) void gemm_fc2(const float* __restrict__ A,
                                                const short* __restrict__ WTh,
                                                const short* __restrict__ WTl,
                                                const float* __restrict__ bias,
                                                float* __restrict__ out, int nrows) {
    __shared__ short Ah[64 * LSTR], Al[64 * LSTR];
    __shared__ short Wh[32 * LSTR], Wl[32 * LSTR];
    const int tid = threadIdx.x;
    const int row0 = blockIdx.x * 64;

    #pragma unroll
    for (int i = 0; i < 16; ++i) {           // A: 64 rows x 32 float4
        int u = i * 128 + tid;
        int r = u >> 5, c4 = u & 31;
        int gr = row0 + r;
        float4 v = make_float4(0.f, 0.f, 0.f, 0.f);
        if (gr < nrows) v = ((const float4*)A)[(size_t)gr * 32 + c4];
        HL px = bsplit(v.x), py = bsplit(v.y), pz = bsplit(v.z), pw = bsplit(v.w);
        s4v h4 = {px.hi, py.hi, pz.hi, pw.hi};
        s4v l4 = {px.lo, py.lo, pz.lo, pw.lo};
        *(s4v*)&Ah[r * LSTR + c4 * 4] = h4;
        *(s4v*)&Al[r * LSTR + c4 * 4] = l4;
    }
    #pragma unroll
    for (int i = 0; i < 4; ++i) {            // W: 32 cols x 16 short8
        int u = i * 128 + tid;
        int c = u >> 4, j = u & 15;
        *(s8v*)&Wh[c * LSTR + j * 8] = *(const s8v*)&WTh[(size_t)c * 128 + j * 8];
        *(s8v*)&Wl[c * LSTR + j * 8] = *(const s8v*)&WTl[(size_t)c * 128 + j * 8];
    }
    __syncthreads();

    const int wv = tid >> 6, lane = tid & 63;
    const int m = lane & 31, half = lane >> 5;
    f16v acc = {0.f};
    #pragma unroll
    for (int ks = 0; ks < 8; ++ks) {
        int ko = ks * 16 + half * 8;
        s8v ah = *(const s8v*)&Ah[(wv * 32 + m) * LSTR + ko];
        s8v al = *(const s8v*)&Al[(wv * 32 + m) * LSTR + ko];
        s8v bh = *(const s8v*)&Wh[m * LSTR + ko];
        s8v bl = *(const s8v*)&Wl[m * LSTR + ko];
        acc = __builtin_amdgcn_mfma_f32_32x32x16_bf16(ah, bh, acc, 0, 0, 0);
        acc = __builtin_amdgcn_mfma_f32_32x32x16_bf16(ah, bl, acc, 0, 0, 0);
        acc = __builtin_amdgcn_mfma_f32_32x32x16_bf16(al, bh, acc, 0, 0, 0);
    }

    #pragma unroll
    for (int reg = 0; reg < 16; ++reg) {
        int rl = (reg & 3) + 8 * (reg >> 2) + 4 * half;
        int gr = row0 + wv * 32 + rl;
        if (gr >= nrows) continue;
        out[(size_t)gr * 32 + m] = acc[reg] + bias[m];
    }
}

// ---------------- launch ----------------

extern "C" void kernel_launch(void* const* d_in, const int* in_sizes, int n_in,
                              void* d_out, int out_size, void* d_ws, size_t ws_size,
                              hipStream_t stream) {
    const float* x    = (const float*)d_in[0];
    const int*   ei   = (const int*)d_in[1];
    const int*   batch= (const int*)d_in[2];
    const float* qe   = (const float*)d_in[3];
    const float* W0   = (const float*)d_in[4];
    const float* b0   = (const float*)d_in[5];
    const float* W1   = (const float*)d_in[6];
    const float* b1   = (const float*)d_in[7];
    const float* W2   = (const float*)d_in[8];
    const float* b2   = (const float*)d_in[9];
    const float* fc0w = (const float*)d_in[10];
    const float* fc0b = (const float*)d_in[11];
    const float* fc1w = (const float*)d_in[12];
    const float* fc1b = (const float*)d_in[13];
    const float* fc2w = (const float*)d_in[14];
    const float* fc2b = (const float*)d_in[15];
    float* out = (float*)d_out;

    float* WS   = (float*)d_ws;
    float* H    = WS;                        // [50000,128]  (Hs = h*dinv)
    float* G    = WS + 6400000;              // [50000,128]
    float* DINV = WS + 12800000;             // [50000]
    float* QQ   = DINV + 50016;              // [64,128]
    int*   CNT  = (int*)(QQ + 8192);         // [50000]
    int*   ROWPTR = CNT + 50000;             // [50001]+pad
    int*   COL  = ROWPTR + 50016;            // [800000]
    int*   BSUM = COL + 800000;              // [128]
    short* WTH  = (short*)(BSUM + 128);      // [69632] hi (W0,W1,W2,fc1top,fc2)
    short* WTL  = WTH + 69632;               // [69632] lo

    const int N = N_NODES, E = N_EDGES;
    const int nb  = (N + 255) / 256;
    const int eb  = (E + 255) / 256;
    const int sb  = (N + 511) / 512;
    const dim3 gg((N + 31) / 32, 2);         // (1563,2)

    // ---- CSR build + normalization ----
    (void)hipMemsetAsync(CNT, 0, N * sizeof(int), stream);
    k_hist<<<eb, 256, 0, stream>>>(ei, CNT, E);
    k_dinv<<<nb, 256, 0, stream>>>(CNT, DINV, N);
    k_scan_a<<<sb, 512, 0, stream>>>(CNT, ROWPTR, BSUM, N);
    k_scan_b<<<1, 128, 0, stream>>>(BSUM, sb);
    k_scan_c<<<sb, 512, 0, stream>>>(ROWPTR, BSUM, N, E);
    (void)hipMemsetAsync(CNT, 0, N * sizeof(int), stream);
    k_fill_csr<<<eb, 256, 0, stream>>>(ei, ROWPTR, CNT, COL, E);

    // ---- weight split / question path ----
    k_wsplit<<<(69632 + 255) / 256, 256, 0, stream>>>(W0, W1, W2, fc1w, fc2w, WTH, WTL);
    k_qq<<<N_GRAPHS, 256, 0, stream>>>(qe, fc0w, fc0b, fc1w + 128 * 128, fc1b, QQ);

    // ---- GCN layers: MFMA gemm (scaled epilogue) -> gather ----
    gemm_mf<0><<<gg, 128, 0, stream>>>(x, WTH, WTL, DINV, nullptr, nullptr, H, N);
    k_gather<<<(N + 3) / 4, 256, 0, stream>>>(H, ROWPTR, COL, DINV, b0, G, N);

    gemm_mf<0><<<gg, 128, 0, stream>>>(G, WTH + 16384, WTL + 16384, DINV, nullptr, nullptr, H, N);
    k_gather<<<(N + 3) / 4, 256, 0, stream>>>(H, ROWPTR, COL, DINV, b1, G, N);

    gemm_mf<0><<<gg, 128, 0, stream>>>(G, WTH + 32768, WTL + 32768, DINV, nullptr, nullptr, H, N);
    k_gather<<<(N + 3) / 4, 256, 0, stream>>>(H, ROWPTR, COL, DINV, b2, G, N);

    // ---- fc1 (concat folded) ----
    gemm_mf<1><<<gg, 128, 0, stream>>>(G, WTH + 49152, WTL + 49152, nullptr, QQ, batch, H, N);
    // ---- fc2 -> d_out ----
    gemm_fc2<<<(N + 63) / 64, 128, 0, stream>>>(H, WTH + 65536, WTL + 65536, fc2b, out, N);
}

// Round 5
// 454.825 us; speedup vs baseline: 1.1725x; 1.1725x over previous
//
#include <hip/hip_runtime.h>
#include <hip/hip_bf16.h>

#define N_NODES 50000
#define N_EDGES 800000
#define N_GRAPHS 64

typedef __attribute__((ext_vector_type(4))) short s4v;
typedef __attribute__((ext_vector_type(8))) short s8v;
typedef __attribute__((ext_vector_type(16))) float f16v;

struct HL { short hi, lo; };

// round-to-nearest-even split of fp32 into bf16 hi + bf16 lo
__device__ inline HL bsplit(float f) {
    HL r;
    unsigned u = __float_as_uint(f);
    unsigned rh = (u + 0x7FFFu + ((u >> 16) & 1u)) >> 16;
    r.hi = (short)rh;
    float fh = __uint_as_float(rh << 16);
    float fl = f - fh;
    unsigned u2 = __float_as_uint(fl);
    unsigned rl = (u2 + 0x7FFFu + ((u2 >> 16) & 1u)) >> 16;
    r.lo = (short)rl;
    return r;
}

__device__ inline unsigned short f2bf(float f) {
    unsigned u = __float_as_uint(f);
    return (unsigned short)((u + 0x7FFFu + ((u >> 16) & 1u)) >> 16);
}

// ---------------- degree / CSR ----------------

__global__ void k_hist(const int* __restrict__ ei, int* __restrict__ cnt, int E) {
    int e = blockIdx.x * 256 + threadIdx.x;
    if (e < E) atomicAdd(&cnt[ei[E + e]], 1);
}

// scan_a also computes dinv (fused)
__global__ __launch_bounds__(512) void k_scan_a(const int* __restrict__ cnt,
                                                int* __restrict__ rowptr,
                                                int* __restrict__ bsum,
                                                float* __restrict__ dinv, int n) {
    __shared__ int s[512];
    int t = threadIdx.x;
    int i = blockIdx.x * 512 + t;
    int v = (i < n) ? cnt[i] : 0;
    if (i < n) dinv[i] = rsqrtf((float)(v + 1));
    s[t] = v;
    __syncthreads();
    for (int d = 1; d < 512; d <<= 1) {
        int x = (t >= d) ? s[t - d] : 0;
        __syncthreads();
        s[t] += x;
        __syncthreads();
    }
    if (i < n) rowptr[i] = s[t] - v;
    if (t == 511) bsum[blockIdx.x] = s[511];
}

__global__ __launch_bounds__(128) void k_scan_b(int* __restrict__ bsum, int nb) {
    __shared__ int s[128];
    int t = threadIdx.x;
    int v = (t < nb) ? bsum[t] : 0;
    s[t] = v;
    __syncthreads();
    for (int d = 1; d < 128; d <<= 1) {
        int x = (t >= d) ? s[t - d] : 0;
        __syncthreads();
        s[t] += x;
        __syncthreads();
    }
    if (t < nb) bsum[t] = s[t] - v;
}

// scan_c also zeroes the fill counters (fused; fill_csr runs after, stream-serial)
__global__ __launch_bounds__(512) void k_scan_c(int* __restrict__ rowptr,
                                                const int* __restrict__ bsum,
                                                int* __restrict__ fill,
                                                int n, int E) {
    int i = blockIdx.x * 512 + threadIdx.x;
    if (i < n) {
        rowptr[i] += bsum[blockIdx.x];
        fill[i] = 0;
    }
    if (i == 0) rowptr[n] = E;
}

__global__ void k_fill_csr(const int* __restrict__ ei, const int* __restrict__ rowptr,
                           int* __restrict__ fill, int* __restrict__ colA, int E) {
    int e = blockIdx.x * 256 + threadIdx.x;
    if (e >= E) return;
    int s = ei[e], d = ei[E + e];
    int pos = rowptr[d] + atomicAdd(&fill[d], 1);
    colA[pos] = s;
}

// ---------------- weight split+transpose precompute ----------------
__global__ void k_wsplit(const float* __restrict__ W0, const float* __restrict__ W1,
                         const float* __restrict__ W2, const float* __restrict__ fc1,
                         const float* __restrict__ fc2w,
                         short* __restrict__ WH, short* __restrict__ WL) {
    int i = blockIdx.x * 256 + threadIdx.x;
    if (i >= 69632) return;
    float val;
    int dst;
    if (i < 65536) {
        int mat = i >> 14, off = i & 16383;
        int k = off >> 7, n = off & 127;
        const float* src = (mat == 0) ? W0 : (mat == 1) ? W1 : (mat == 2) ? W2 : fc1;
        val = src[k * 128 + n];
        dst = mat * 16384 + n * 128 + k;
    } else {
        int off = i - 65536;
        int k = off >> 5, n = off & 31;
        val = fc2w[k * 32 + n];
        dst = 65536 + n * 128 + k;
    }
    HL r = bsplit(val);
    WH[dst] = r.hi;
    WL[dst] = r.lo;
}

// ---------------- question path (4-way k-split, 512 threads) ----------------
__global__ __launch_bounds__(512) void k_qq(const float* __restrict__ qe,
                                            const float* __restrict__ fc0w,
                                            const float* __restrict__ fc0b,
                                            const float* __restrict__ fc1bot,
                                            const float* __restrict__ fc1b,
                                            float* __restrict__ qq) {
    int g = blockIdx.x, tid = threadIdx.x;
    __shared__ float qs[768];
    __shared__ float red[512];
    __shared__ float ql[128];
    for (int i = tid; i < 768; i += 512) qs[i] = qe[g * 768 + i];
    __syncthreads();
    int j = tid & 127, sl = tid >> 7;          // slice 0..3
    int kb = sl * 192;
    float a0 = 0, a1 = 0, a2 = 0, a3 = 0;
    for (int k = 0; k < 192; k += 4) {
        a0 += qs[kb + k + 0] * fc0w[(kb + k + 0) * 128 + j];
        a1 += qs[kb + k + 1] * fc0w[(kb + k + 1) * 128 + j];
        a2 += qs[kb + k + 2] * fc0w[(kb + k + 2) * 128 + j];
        a3 += qs[kb + k + 3] * fc0w[(kb + k + 3) * 128 + j];
    }
    red[tid] = (a0 + a1) + (a2 + a3);
    __syncthreads();
    if (tid < 128)
        ql[tid] = fmaxf(((red[tid] + red[tid + 128]) + (red[tid + 256] + red[tid + 384]))
                        + fc0b[tid], 0.f);
    __syncthreads();
    kb = sl * 32;
    float b0 = 0, b1 = 0;
    for (int k = 0; k < 32; k += 2) {
        b0 += ql[kb + k + 0] * fc1bot[(kb + k + 0) * 128 + j];
        b1 += ql[kb + k + 1] * fc1bot[(kb + k + 1) * 128 + j];
    }
    red[tid] = b0 + b1;
    __syncthreads();
    if (tid < 128)
        qq[g * 128 + tid] = ((red[tid] + red[tid + 128]) + (red[tid + 256] + red[tid + 384]))
                            + fc1b[tid];
}

// ---------------- CSR gather over bf16 Hs ----------------
// Hs[node][f] bf16, prescaled by dinv[row]. Lane loads 1 dword = features 2*lane, 2*lane+1.
// out[node] = relu((sum_src Hs[src] + Hs[node]) * dinv[node] + b)   (fp32 out)
__global__ __launch_bounds__(256) void k_gather(const unsigned int* __restrict__ Hs,
                                                const int* __restrict__ rowptr,
                                                const int* __restrict__ colA,
                                                const float* __restrict__ dinv,
                                                const float* __restrict__ bias,
                                                float* __restrict__ outp, int n) {
    int node = __builtin_amdgcn_readfirstlane(blockIdx.x * 4 + (threadIdx.x >> 6));
    if (node >= n) return;
    int lane = threadIdx.x & 63;
    int e0 = rowptr[node], e1 = rowptr[node + 1];
    float ax = 0.f, ay = 0.f;                   // even / odd feature
    int e = e0;
    for (; e + 8 <= e1; e += 8) {
        int s0 = colA[e], s1 = colA[e + 1], s2 = colA[e + 2], s3 = colA[e + 3];
        int s4 = colA[e + 4], s5 = colA[e + 5], s6 = colA[e + 6], s7 = colA[e + 7];
        unsigned u0 = Hs[(size_t)s0 * 64 + lane];
        unsigned u1 = Hs[(size_t)s1 * 64 + lane];
        unsigned u2 = Hs[(size_t)s2 * 64 + lane];
        unsigned u3 = Hs[(size_t)s3 * 64 + lane];
        unsigned u4 = Hs[(size_t)s4 * 64 + lane];
        unsigned u5 = Hs[(size_t)s5 * 64 + lane];
        unsigned u6 = Hs[(size_t)s6 * 64 + lane];
        unsigned u7 = Hs[(size_t)s7 * 64 + lane];
        ax += (__uint_as_float(u0 << 16) + __uint_as_float(u1 << 16))
            + (__uint_as_float(u2 << 16) + __uint_as_float(u3 << 16))
            + (__uint_as_float(u4 << 16) + __uint_as_float(u5 << 16))
            + (__uint_as_float(u6 << 16) + __uint_as_float(u7 << 16));
        ay += (__uint_as_float(u0 & 0xFFFF0000u) + __uint_as_float(u1 & 0xFFFF0000u))
            + (__uint_as_float(u2 & 0xFFFF0000u) + __uint_as_float(u3 & 0xFFFF0000u))
            + (__uint_as_float(u4 & 0xFFFF0000u) + __uint_as_float(u5 & 0xFFFF0000u))
            + (__uint_as_float(u6 & 0xFFFF0000u) + __uint_as_float(u7 & 0xFFFF0000u));
    }
    for (; e < e1; ++e) {
        unsigned u = Hs[(size_t)colA[e] * 64 + lane];
        ax += __uint_as_float(u << 16);
        ay += __uint_as_float(u & 0xFFFF0000u);
    }
    float di = dinv[node];
    unsigned uh = Hs[(size_t)node * 64 + lane];
    float2 bb = ((const float2*)bias)[lane];
    float2 o;
    o.x = fmaxf((ax + __uint_as_float(uh << 16)) * di + bb.x, 0.f);
    o.y = fmaxf((ay + __uint_as_float(uh & 0xFFFF0000u)) * di + bb.y, 0.f);
    ((float2*)(outp + (size_t)node * 128))[lane] = o;
}

// ---------------- 3xBF16-split MFMA GEMM: [N,128]@[128,128] ----------------
// MODE 0: Hs_bf16 = (A@W) * dinv[row]      MODE 1: out_f32 = relu(A@W + qq[batch[row]])
#define LSTR 136
template <int MODE>
__global__ __launch_bounds__(128) void gemm_mf(const float* __restrict__ A,
                                               const short* __restrict__ WTh,
                                               const short* __restrict__ WTl,
                                               const float* __restrict__ dinv,
                                               const float* __restrict__ qq,
                                               const int* __restrict__ batch,
                                               void* __restrict__ outv, int nrows) {
    __shared__ short Ah[32 * LSTR], Al[32 * LSTR];
    __shared__ short Wh[64 * LSTR], Wl[64 * LSTR];
    const int tid = threadIdx.x;
    const int row0 = blockIdx.x * 32;
    const int col0 = blockIdx.y * 64;

    #pragma unroll
    for (int i = 0; i < 8; ++i) {
        int u = i * 128 + tid;
        int r = u >> 5, c4 = u & 31;
        int gr = row0 + r;
        float4 v = make_float4(0.f, 0.f, 0.f, 0.f);
        if (gr < nrows) v = ((const float4*)A)[(size_t)gr * 32 + c4];
        HL px = bsplit(v.x), py = bsplit(v.y), pz = bsplit(v.z), pw = bsplit(v.w);
        s4v h4 = {px.hi, py.hi, pz.hi, pw.hi};
        s4v l4 = {px.lo, py.lo, pz.lo, pw.lo};
        *(s4v*)&Ah[r * LSTR + c4 * 4] = h4;
        *(s4v*)&Al[r * LSTR + c4 * 4] = l4;
    }
    #pragma unroll
    for (int i = 0; i < 8; ++i) {
        int u = i * 128 + tid;
        int c = u >> 4, j = u & 15;
        *(s8v*)&Wh[c * LSTR + j * 8] = *(const s8v*)&WTh[(size_t)(col0 + c) * 128 + j * 8];
        *(s8v*)&Wl[c * LSTR + j * 8] = *(const s8v*)&WTl[(size_t)(col0 + c) * 128 + j * 8];
    }
    __syncthreads();

    const int wv = tid >> 6, lane = tid & 63;
    const int m = lane & 31, half = lane >> 5;
    const int colb = wv * 32;
    f16v acc = {0.f};
    #pragma unroll
    for (int ks = 0; ks < 8; ++ks) {
        int ko = ks * 16 + half * 8;
        s8v ah = *(const s8v*)&Ah[m * LSTR + ko];
        s8v al = *(const s8v*)&Al[m * LSTR + ko];
        s8v bh = *(const s8v*)&Wh[(colb + m) * LSTR + ko];
        s8v bl = *(const s8v*)&Wl[(colb + m) * LSTR + ko];
        acc = __builtin_amdgcn_mfma_f32_32x32x16_bf16(ah, bh, acc, 0, 0, 0);
        acc = __builtin_amdgcn_mfma_f32_32x32x16_bf16(ah, bl, acc, 0, 0, 0);
        acc = __builtin_amdgcn_mfma_f32_32x32x16_bf16(al, bh, acc, 0, 0, 0);
    }

    #pragma unroll
    for (int reg = 0; reg < 16; ++reg) {
        int rl = (reg & 3) + 8 * (reg >> 2) + 4 * half;
        int gr = row0 + rl;
        if (gr >= nrows) continue;
        int gc = col0 + colb + m;
        if (MODE == 0) {
            ((unsigned short*)outv)[(size_t)gr * 128 + gc] = f2bf(acc[reg] * dinv[gr]);
        } else {
            float v = fmaxf(acc[reg] + qq[(size_t)batch[gr] * 128 + gc], 0.f);
            ((float*)outv)[(size_t)gr * 128 + gc] = v;
        }
    }
}

// ---------------- fc2: [N,128]@[128,32] + b (3xBF16 MFMA) ----------------
__global__ __launch_bounds__(128) void gemm_fc2(const float* __restrict__ A,
                                                const short* __restrict__ WTh,
                                                const short* __restrict__ WTl,
                                                const float* __restrict__ bias,
                                                float* __restrict__ out, int nrows) {
    __shared__ short Ah[64 * LSTR], Al[64 * LSTR];
    __shared__ short Wh[32 * LSTR], Wl[32 * LSTR];
    const int tid = threadIdx.x;
    const int row0 = blockIdx.x * 64;

    #pragma unroll
    for (int i = 0; i < 16; ++i) {
        int u = i * 128 + tid;
        int r = u >> 5, c4 = u & 31;
        int gr = row0 + r;
        float4 v = make_float4(0.f, 0.f, 0.f, 0.f);
        if (gr < nrows) v = ((const float4*)A)[(size_t)gr * 32 + c4];
        HL px = bsplit(v.x), py = bsplit(v.y), pz = bsplit(v.z), pw = bsplit(v.w);
        s4v h4 = {px.hi, py.hi, pz.hi, pw.hi};
        s4v l4 = {px.lo, py.lo, pz.lo, pw.lo};
        *(s4v*)&Ah[r * LSTR + c4 * 4] = h4;
        *(s4v*)&Al[r * LSTR + c4 * 4] = l4;
    }
    #pragma unroll
    for (int i = 0; i < 4; ++i) {
        int u = i * 128 + tid;
        int c = u >> 4, j = u & 15;
        *(s8v*)&Wh[c * LSTR + j * 8] = *(const s8v*)&WTh[(size_t)c * 128 + j * 8];
        *(s8v*)&Wl[c * LSTR + j * 8] = *(const s8v*)&WTl[(size_t)c * 128 + j * 8];
    }
    __syncthreads();

    const int wv = tid >> 6, lane = tid & 63;
    const int m = lane & 31, half = lane >> 5;
    f16v acc = {0.f};
    #pragma unroll
    for (int ks = 0; ks < 8; ++ks) {
        int ko = ks * 16 + half * 8;
        s8v ah = *(const s8v*)&Ah[(wv * 32 + m) * LSTR + ko];
        s8v al = *(const s8v*)&Al[(wv * 32 + m) * LSTR + ko];
        s8v bh = *(const s8v*)&Wh[m * LSTR + ko];
        s8v bl = *(const s8v*)&Wl[m * LSTR + ko];
        acc = __builtin_amdgcn_mfma_f32_32x32x16_bf16(ah, bh, acc, 0, 0, 0);
        acc = __builtin_amdgcn_mfma_f32_32x32x16_bf16(ah, bl, acc, 0, 0, 0);
        acc = __builtin_amdgcn_mfma_f32_32x32x16_bf16(al, bh, acc, 0, 0, 0);
    }

    #pragma unroll
    for (int reg = 0; reg < 16; ++reg) {
        int rl = (reg & 3) + 8 * (reg >> 2) + 4 * half;
        int gr = row0 + wv * 32 + rl;
        if (gr >= nrows) continue;
        out[(size_t)gr * 32 + m] = acc[reg] + bias[m];
    }
}

// ---------------- launch ----------------

extern "C" void kernel_launch(void* const* d_in, const int* in_sizes, int n_in,
                              void* d_out, int out_size, void* d_ws, size_t ws_size,
                              hipStream_t stream) {
    const float* x    = (const float*)d_in[0];
    const int*   ei   = (const int*)d_in[1];
    const int*   batch= (const int*)d_in[2];
    const float* qe   = (const float*)d_in[3];
    const float* W0   = (const float*)d_in[4];
    const float* b0   = (const float*)d_in[5];
    const float* W1   = (const float*)d_in[6];
    const float* b1   = (const float*)d_in[7];
    const float* W2   = (const float*)d_in[8];
    const float* b2   = (const float*)d_in[9];
    const float* fc0w = (const float*)d_in[10];
    const float* fc0b = (const float*)d_in[11];
    const float* fc1w = (const float*)d_in[12];
    const float* fc1b = (const float*)d_in[13];
    const float* fc2w = (const float*)d_in[14];
    const float* fc2b = (const float*)d_in[15];
    float* out = (float*)d_out;

    float* WS   = (float*)d_ws;
    float* H    = WS;                        // fp32 [50000,128] (fc1 out) / bf16 Hs view
    float* G    = WS + 6400000;              // fp32 [50000,128]
    float* DINV = WS + 12800000;             // [50000]
    float* QQ   = DINV + 50016;              // [64,128]
    int*   CNT  = (int*)(QQ + 8192);         // [50000] (deg, then fill)
    int*   ROWPTR = CNT + 50000;             // [50001]+pad
    int*   COL  = ROWPTR + 50016;            // [800000]
    int*   BSUM = COL + 800000;              // [128]
    short* WTH  = (short*)(BSUM + 128);      // [69632]
    short* WTL  = WTH + 69632;               // [69632]
    unsigned short* HS = (unsigned short*)H; // bf16 [50000,128]

    const int N = N_NODES, E = N_EDGES;
    const int eb  = (E + 255) / 256;
    const int sb  = (N + 511) / 512;
    const dim3 gg((N + 31) / 32, 2);

    // ---- CSR build (+dinv, +fill-zero fused) ----
    (void)hipMemsetAsync(CNT, 0, N * sizeof(int), stream);
    k_hist<<<eb, 256, 0, stream>>>(ei, CNT, E);
    k_scan_a<<<sb, 512, 0, stream>>>(CNT, ROWPTR, BSUM, DINV, N);
    k_scan_b<<<1, 128, 0, stream>>>(BSUM, sb);
    k_scan_c<<<sb, 512, 0, stream>>>(ROWPTR, BSUM, CNT, N, E);
    k_fill_csr<<<eb, 256, 0, stream>>>(ei, ROWPTR, CNT, COL, E);

    // ---- weight split / question path ----
    k_wsplit<<<(69632 + 255) / 256, 256, 0, stream>>>(W0, W1, W2, fc1w, fc2w, WTH, WTL);
    k_qq<<<N_GRAPHS, 512, 0, stream>>>(qe, fc0w, fc0b, fc1w + 128 * 128, fc1b, QQ);

    // ---- GCN layers: MFMA gemm (bf16 Hs epilogue) -> bf16 gather ----
    gemm_mf<0><<<gg, 128, 0, stream>>>(x, WTH, WTL, DINV, nullptr, nullptr, HS, N);
    k_gather<<<(N + 3) / 4, 256, 0, stream>>>((const unsigned int*)HS, ROWPTR, COL, DINV, b0, G, N);

    gemm_mf<0><<<gg, 128, 0, stream>>>(G, WTH + 16384, WTL + 16384, DINV, nullptr, nullptr, HS, N);
    k_gather<<<(N + 3) / 4, 256, 0, stream>>>((const unsigned int*)HS, ROWPTR, COL, DINV, b1, G, N);

    gemm_mf<0><<<gg, 128, 0, stream>>>(G, WTH + 32768, WTL + 32768, DINV, nullptr, nullptr, HS, N);
    k_gather<<<(N + 3) / 4, 256, 0, stream>>>((const unsigned int*)HS, ROWPTR, COL, DINV, b2, G, N);

    // ---- fc1 (concat folded) -> fp32 H ----
    gemm_mf<1><<<gg, 128, 0, stream>>>(G, WTH + 49152, WTL + 49152, nullptr, QQ, batch, H, N);
    // ---- fc2 -> d_out ----
    gemm_fc2<<<(N + 63) / 64, 128, 0, stream>>>(H, WTH + 65536, WTL + 65536, fc2b, out, N);
}

// Round 6
// 443.791 us; speedup vs baseline: 1.2016x; 1.0249x over previous
//
#include <hip/hip_runtime.h>
#include <hip/hip_bf16.h>

#define N_NODES 50000
#define N_EDGES 800000
#define N_GRAPHS 64

typedef __attribute__((ext_vector_type(4))) short s4v;
typedef __attribute__((ext_vector_type(8))) short s8v;
typedef __attribute__((ext_vector_type(16))) float f16v;

struct HL { short hi, lo; };

// round-to-nearest-even split of fp32 into bf16 hi + bf16 lo
__device__ inline HL bsplit(float f) {
    HL r;
    unsigned u = __float_as_uint(f);
    unsigned rh = (u + 0x7FFFu + ((u >> 16) & 1u)) >> 16;
    r.hi = (short)rh;
    float fh = __uint_as_float(rh << 16);
    float fl = f - fh;
    unsigned u2 = __float_as_uint(fl);
    unsigned rl = (u2 + 0x7FFFu + ((u2 >> 16) & 1u)) >> 16;
    r.lo = (short)rl;
    return r;
}

__device__ inline unsigned short f2bf(float f) {
    unsigned u = __float_as_uint(f);
    return (unsigned short)((u + 0x7FFFu + ((u >> 16) & 1u)) >> 16);
}

__device__ inline float bflo(unsigned u) { return __uint_as_float(u << 16); }
__device__ inline float bfhi(unsigned u) { return __uint_as_float(u & 0xFFFF0000u); }

// ---------------- degree / CSR ----------------

// hist also records each edge's rank within its dst row (coalesced write)
__global__ void k_hist(const int* __restrict__ ei, int* __restrict__ cnt,
                       int* __restrict__ rank, int E) {
    int e = blockIdx.x * 256 + threadIdx.x;
    if (e < E) rank[e] = atomicAdd(&cnt[ei[E + e]], 1);
}

// scan_a also computes dinv (fused)
__global__ __launch_bounds__(512) void k_scan_a(const int* __restrict__ cnt,
                                                int* __restrict__ rowptr,
                                                int* __restrict__ bsum,
                                                float* __restrict__ dinv, int n) {
    __shared__ int s[512];
    int t = threadIdx.x;
    int i = blockIdx.x * 512 + t;
    int v = (i < n) ? cnt[i] : 0;
    if (i < n) dinv[i] = rsqrtf((float)(v + 1));
    s[t] = v;
    __syncthreads();
    for (int d = 1; d < 512; d <<= 1) {
        int x = (t >= d) ? s[t - d] : 0;
        __syncthreads();
        s[t] += x;
        __syncthreads();
    }
    if (i < n) rowptr[i] = s[t] - v;
    if (t == 511) bsum[blockIdx.x] = s[511];
}

__global__ __launch_bounds__(128) void k_scan_b(int* __restrict__ bsum, int nb) {
    __shared__ int s[128];
    int t = threadIdx.x;
    int v = (t < nb) ? bsum[t] : 0;
    s[t] = v;
    __syncthreads();
    for (int d = 1; d < 128; d <<= 1) {
        int x = (t >= d) ? s[t - d] : 0;
        __syncthreads();
        s[t] += x;
        __syncthreads();
    }
    if (t < nb) bsum[t] = s[t] - v;
}

__global__ __launch_bounds__(512) void k_scan_c(int* __restrict__ rowptr,
                                                const int* __restrict__ bsum,
                                                int n, int E) {
    int i = blockIdx.x * 512 + threadIdx.x;
    if (i < n) rowptr[i] += bsum[blockIdx.x];
    if (i == 0) rowptr[n] = E;
}

// no atomic: position = rowptr[dst] + rank[e]
__global__ void k_fill_csr(const int* __restrict__ ei, const int* __restrict__ rowptr,
                           const int* __restrict__ rank, int* __restrict__ colA, int E) {
    int e = blockIdx.x * 256 + threadIdx.x;
    if (e >= E) return;
    colA[rowptr[ei[E + e]] + rank[e]] = ei[e];
}

// ---------------- weight split+transpose precompute ----------------
__global__ void k_wsplit(const float* __restrict__ W0, const float* __restrict__ W1,
                         const float* __restrict__ W2, const float* __restrict__ fc1,
                         const float* __restrict__ fc2w,
                         short* __restrict__ WH, short* __restrict__ WL) {
    int i = blockIdx.x * 256 + threadIdx.x;
    if (i >= 69632) return;
    float val;
    int dst;
    if (i < 65536) {
        int mat = i >> 14, off = i & 16383;
        int k = off >> 7, n = off & 127;
        const float* src = (mat == 0) ? W0 : (mat == 1) ? W1 : (mat == 2) ? W2 : fc1;
        val = src[k * 128 + n];
        dst = mat * 16384 + n * 128 + k;
    } else {
        int off = i - 65536;
        int k = off >> 5, n = off & 31;
        val = fc2w[k * 32 + n];
        dst = 65536 + n * 128 + k;
    }
    HL r = bsplit(val);
    WH[dst] = r.hi;
    WL[dst] = r.lo;
}

// ---------------- question path (4-way k-split, 512 threads) ----------------
__global__ __launch_bounds__(512) void k_qq(const float* __restrict__ qe,
                                            const float* __restrict__ fc0w,
                                            const float* __restrict__ fc0b,
                                            const float* __restrict__ fc1bot,
                                            const float* __restrict__ fc1b,
                                            float* __restrict__ qq) {
    int g = blockIdx.x, tid = threadIdx.x;
    __shared__ float qs[768];
    __shared__ float red[512];
    __shared__ float ql[128];
    for (int i = tid; i < 768; i += 512) qs[i] = qe[g * 768 + i];
    __syncthreads();
    int j = tid & 127, sl = tid >> 7;
    int kb = sl * 192;
    float a0 = 0, a1 = 0, a2 = 0, a3 = 0;
    for (int k = 0; k < 192; k += 4) {
        a0 += qs[kb + k + 0] * fc0w[(kb + k + 0) * 128 + j];
        a1 += qs[kb + k + 1] * fc0w[(kb + k + 1) * 128 + j];
        a2 += qs[kb + k + 2] * fc0w[(kb + k + 2) * 128 + j];
        a3 += qs[kb + k + 3] * fc0w[(kb + k + 3) * 128 + j];
    }
    red[tid] = (a0 + a1) + (a2 + a3);
    __syncthreads();
    if (tid < 128)
        ql[tid] = fmaxf(((red[tid] + red[tid + 128]) + (red[tid + 256] + red[tid + 384]))
                        + fc0b[tid], 0.f);
    __syncthreads();
    kb = sl * 32;
    float b0 = 0, b1 = 0;
    for (int k = 0; k < 32; k += 2) {
        b0 += ql[kb + k + 0] * fc1bot[(kb + k + 0) * 128 + j];
        b1 += ql[kb + k + 1] * fc1bot[(kb + k + 1) * 128 + j];
    }
    red[tid] = b0 + b1;
    __syncthreads();
    if (tid < 128)
        qq[g * 128 + tid] = ((red[tid] + red[tid + 128]) + (red[tid + 256] + red[tid + 384]))
                            + fc1b[tid];
}

// ---------------- CSR gather over bf16 Hs, 2 feature phases, 2 edges/wave ----------------
// grid (ceil(n/4), 2): y = feature half (x-major dispatch => phases ~serialize for L2 reuse)
// Each half-wave handles alternate edges; lane loads 1 dword = 2 bf16 features.
// Output: split bf16 planes GH/GL (numerically ~fp32).
__global__ __launch_bounds__(256) void k_gather(const unsigned* __restrict__ Hs,
                                                const int* __restrict__ rowptr,
                                                const int* __restrict__ colA,
                                                const float* __restrict__ dinv,
                                                const float* __restrict__ bias,
                                                unsigned* __restrict__ GH,
                                                unsigned* __restrict__ GL, int n) {
    int node = __builtin_amdgcn_readfirstlane(blockIdx.x * 4 + (threadIdx.x >> 6));
    if (node >= n) return;
    int fh = blockIdx.y;                        // feature half: dwords fh*32..fh*32+31
    int lane = threadIdx.x & 63;
    int h = lane >> 5, l5 = lane & 31;
    const unsigned* base = Hs + (size_t)fh * 32 + l5;    // + s*64
    int e0 = rowptr[node], e1 = rowptr[node + 1];
    float a0 = 0.f, a1 = 0.f;
    int e = e0;
    for (; e + 8 <= e1; e += 8) {               // 4 edges per half-wave
        int s0 = colA[e + h], s1 = colA[e + 2 + h];
        int s2 = colA[e + 4 + h], s3 = colA[e + 6 + h];
        unsigned u0 = base[(size_t)s0 * 64];
        unsigned u1 = base[(size_t)s1 * 64];
        unsigned u2 = base[(size_t)s2 * 64];
        unsigned u3 = base[(size_t)s3 * 64];
        a0 += (bflo(u0) + bflo(u1)) + (bflo(u2) + bflo(u3));
        a1 += (bfhi(u0) + bfhi(u1)) + (bfhi(u2) + bfhi(u3));
    }
    for (; e + 2 <= e1; e += 2) {
        unsigned u = base[(size_t)colA[e + h] * 64];
        a0 += bflo(u);
        a1 += bfhi(u);
    }
    if (h == 0 && e < e1) {                     // odd tail edge on half 0
        unsigned u = base[(size_t)colA[e] * 64];
        a0 += bflo(u);
        a1 += bfhi(u);
    }
    a0 += __shfl_down(a0, 32);
    a1 += __shfl_down(a1, 32);
    if (h == 0) {
        float di = dinv[node];
        unsigned uh = base[(size_t)node * 64];
        float2 bb = ((const float2*)bias)[fh * 32 + l5];
        float o0 = fmaxf((a0 + bflo(uh)) * di + bb.x, 0.f);
        float o1 = fmaxf((a1 + bfhi(uh)) * di + bb.y, 0.f);
        HL p0 = bsplit(o0), p1 = bsplit(o1);
        unsigned hp = ((unsigned)(unsigned short)p0.hi) | (((unsigned)(unsigned short)p1.hi) << 16);
        unsigned lp = ((unsigned)(unsigned short)p0.lo) | (((unsigned)(unsigned short)p1.lo) << 16);
        size_t idx = (size_t)node * 64 + fh * 32 + l5;
        GH[idx] = hp;
        GL[idx] = lp;
    }
}

// ---------------- 3xBF16-split MFMA GEMM: [N,128]@[128,128] ----------------
// SPLITIN 0: A fp32 (bsplit on the fly)   SPLITIN 1: A presplit bf16 planes
// MODE 0: Hs_bf16 = (A@W)*dinv[row]       MODE 1: planes = bsplit(relu(A@W + qq[batch]))
#define LSTR 136
template <int MODE, int SPLITIN>
__global__ __launch_bounds__(128) void gemm_mf(const float* __restrict__ A32,
                                               const unsigned short* __restrict__ Ahp,
                                               const unsigned short* __restrict__ Alp,
                                               const short* __restrict__ WTh,
                                               const short* __restrict__ WTl,
                                               const float* __restrict__ dinv,
                                               const float* __restrict__ qq,
                                               const int* __restrict__ batch,
                                               unsigned short* __restrict__ oHs,
                                               unsigned short* __restrict__ oHh,
                                               unsigned short* __restrict__ oHl,
                                               int nrows) {
    __shared__ short Ah[32 * LSTR], Al[32 * LSTR];
    __shared__ short Wh[64 * LSTR], Wl[64 * LSTR];
    const int tid = threadIdx.x;
    const int row0 = blockIdx.x * 32;
    const int col0 = blockIdx.y * 64;

    if (SPLITIN == 0) {
        #pragma unroll
        for (int i = 0; i < 8; ++i) {
            int u = i * 128 + tid;
            int r = u >> 5, c4 = u & 31;
            int gr = row0 + r;
            float4 v = make_float4(0.f, 0.f, 0.f, 0.f);
            if (gr < nrows) v = ((const float4*)A32)[(size_t)gr * 32 + c4];
            HL px = bsplit(v.x), py = bsplit(v.y), pz = bsplit(v.z), pw = bsplit(v.w);
            s4v h4 = {px.hi, py.hi, pz.hi, pw.hi};
            s4v l4 = {px.lo, py.lo, pz.lo, pw.lo};
            *(s4v*)&Ah[r * LSTR + c4 * 4] = h4;
            *(s4v*)&Al[r * LSTR + c4 * 4] = l4;
        }
    } else {
        #pragma unroll
        for (int i = 0; i < 4; ++i) {
            int u = i * 128 + tid;
            int r = u >> 4, j = u & 15;
            int gr = row0 + r;
            s8v h8 = {}, l8 = {};
            if (gr < nrows) {
                h8 = *(const s8v*)&Ahp[(size_t)gr * 128 + j * 8];
                l8 = *(const s8v*)&Alp[(size_t)gr * 128 + j * 8];
            }
            *(s8v*)&Ah[r * LSTR + j * 8] = h8;
            *(s8v*)&Al[r * LSTR + j * 8] = l8;
        }
    }
    #pragma unroll
    for (int i = 0; i < 8; ++i) {
        int u = i * 128 + tid;
        int c = u >> 4, j = u & 15;
        *(s8v*)&Wh[c * LSTR + j * 8] = *(const s8v*)&WTh[(size_t)(col0 + c) * 128 + j * 8];
        *(s8v*)&Wl[c * LSTR + j * 8] = *(const s8v*)&WTl[(size_t)(col0 + c) * 128 + j * 8];
    }
    __syncthreads();

    const int wv = tid >> 6, lane = tid & 63;
    const int m = lane & 31, half = lane >> 5;
    const int colb = wv * 32;
    f16v acc = {0.f};
    #pragma unroll
    for (int ks = 0; ks < 8; ++ks) {
        int ko = ks * 16 + half * 8;
        s8v ah = *(const s8v*)&Ah[m * LSTR + ko];
        s8v al = *(const s8v*)&Al[m * LSTR + ko];
        s8v bh = *(const s8v*)&Wh[(colb + m) * LSTR + ko];
        s8v bl = *(const s8v*)&Wl[(colb + m) * LSTR + ko];
        acc = __builtin_amdgcn_mfma_f32_32x32x16_bf16(ah, bh, acc, 0, 0, 0);
        acc = __builtin_amdgcn_mfma_f32_32x32x16_bf16(ah, bl, acc, 0, 0, 0);
        acc = __builtin_amdgcn_mfma_f32_32x32x16_bf16(al, bh, acc, 0, 0, 0);
    }

    #pragma unroll
    for (int reg = 0; reg < 16; ++reg) {
        int rl = (reg & 3) + 8 * (reg >> 2) + 4 * half;
        int gr = row0 + rl;
        if (gr >= nrows) continue;
        int gc = col0 + colb + m;
        if (MODE == 0) {
            oHs[(size_t)gr * 128 + gc] = f2bf(acc[reg] * dinv[gr]);
        } else {
            float v = fmaxf(acc[reg] + qq[(size_t)batch[gr] * 128 + gc], 0.f);
            HL p = bsplit(v);
            oHh[(size_t)gr * 128 + gc] = (unsigned short)p.hi;
            oHl[(size_t)gr * 128 + gc] = (unsigned short)p.lo;
        }
    }
}

// ---------------- fc2: [N,128]@[128,32] + b, presplit A planes ----------------
__global__ __launch_bounds__(128) void gemm_fc2(const unsigned short* __restrict__ Ahp,
                                                const unsigned short* __restrict__ Alp,
                                                const short* __restrict__ WTh,
                                                const short* __restrict__ WTl,
                                                const float* __restrict__ bias,
                                                float* __restrict__ out, int nrows) {
    __shared__ short Ah[64 * LSTR], Al[64 * LSTR];
    __shared__ short Wh[32 * LSTR], Wl[32 * LSTR];
    const int tid = threadIdx.x;
    const int row0 = blockIdx.x * 64;

    #pragma unroll
    for (int i = 0; i < 8; ++i) {
        int u = i * 128 + tid;
        int r = u >> 4, j = u & 15;
        int gr = row0 + r;
        s8v h8 = {}, l8 = {};
        if (gr < nrows) {
            h8 = *(const s8v*)&Ahp[(size_t)gr * 128 + j * 8];
            l8 = *(const s8v*)&Alp[(size_t)gr * 128 + j * 8];
        }
        *(s8v*)&Ah[r * LSTR + j * 8] = h8;
        *(s8v*)&Al[r * LSTR + j * 8] = l8;
    }
    #pragma unroll
    for (int i = 0; i < 4; ++i) {
        int u = i * 128 + tid;
        int c = u >> 4, j = u & 15;
        *(s8v*)&Wh[c * LSTR + j * 8] = *(const s8v*)&WTh[(size_t)c * 128 + j * 8];
        *(s8v*)&Wl[c * LSTR + j * 8] = *(const s8v*)&WTl[(size_t)c * 128 + j * 8];
    }
    __syncthreads();

    const int wv = tid >> 6, lane = tid & 63;
    const int m = lane & 31, half = lane >> 5;
    f16v acc = {0.f};
    #pragma unroll
    for (int ks = 0; ks < 8; ++ks) {
        int ko = ks * 16 + half * 8;
        s8v ah = *(const s8v*)&Ah[(wv * 32 + m) * LSTR + ko];
        s8v al = *(const s8v*)&Al[(wv * 32 + m) * LSTR + ko];
        s8v bh = *(const s8v*)&Wh[m * LSTR + ko];
        s8v bl = *(const s8v*)&Wl[m * LSTR + ko];
        acc = __builtin_amdgcn_mfma_f32_32x32x16_bf16(ah, bh, acc, 0, 0, 0);
        acc = __builtin_amdgcn_mfma_f32_32x32x16_bf16(ah, bl, acc, 0, 0, 0);
        acc = __builtin_amdgcn_mfma_f32_32x32x16_bf16(al, bh, acc, 0, 0, 0);
    }

    #pragma unroll
    for (int reg = 0; reg < 16; ++reg) {
        int rl = (reg & 3) + 8 * (reg >> 2) + 4 * half;
        int gr = row0 + wv * 32 + rl;
        if (gr >= nrows) continue;
        out[(size_t)gr * 32 + m] = acc[reg] + bias[m];
    }
}

// ---------------- launch ----------------

extern "C" void kernel_launch(void* const* d_in, const int* in_sizes, int n_in,
                              void* d_out, int out_size, void* d_ws, size_t ws_size,
                              hipStream_t stream) {
    const float* x    = (const float*)d_in[0];
    const int*   ei   = (const int*)d_in[1];
    const int*   batch= (const int*)d_in[2];
    const float* qe   = (const float*)d_in[3];
    const float* W0   = (const float*)d_in[4];
    const float* b0   = (const float*)d_in[5];
    const float* W1   = (const float*)d_in[6];
    const float* b1   = (const float*)d_in[7];
    const float* W2   = (const float*)d_in[8];
    const float* b2   = (const float*)d_in[9];
    const float* fc0w = (const float*)d_in[10];
    const float* fc0b = (const float*)d_in[11];
    const float* fc1w = (const float*)d_in[12];
    const float* fc1b = (const float*)d_in[13];
    const float* fc2w = (const float*)d_in[14];
    const float* fc2b = (const float*)d_in[15];
    float* out = (float*)d_out;

    float* WS = (float*)d_ws;
    unsigned short* HS = (unsigned short*)WS;            // bf16 [50000,128] (aliased by HH)
    unsigned short* GH = (unsigned short*)(WS + 3200000);
    unsigned short* GL = (unsigned short*)(WS + 6400000);
    unsigned short* HH = HS;                              // fc1 out hi (Hs dead by then)
    unsigned short* HL = (unsigned short*)(WS + 9600000);
    float* DINV = WS + 12800000;             // [50016]
    float* QQ   = WS + 12850016;             // [8192]
    int*   CNT  = (int*)(WS + 12858208);     // [50016]
    int*   ROWPTR = (int*)(WS + 12908224);   // [50016]
    int*   RANK = (int*)(WS + 12958240);     // [800000]
    int*   COL  = (int*)(WS + 13758240);     // [800000]
    int*   BSUM = (int*)(WS + 14558240);     // [128]
    short* WTH  = (short*)(WS + 14558368);   // [69632]
    short* WTL  = WTH + 69632;               // [69632]

    const int N = N_NODES, E = N_EDGES;
    const int eb = (E + 255) / 256;
    const int sb = (N + 511) / 512;
    const dim3 gg((N + 31) / 32, 2);
    const dim3 gat((N + 3) / 4, 2);

    // ---- CSR build (rank-fused hist; atomic-free fill) ----
    (void)hipMemsetAsync(CNT, 0, N * sizeof(int), stream);
    k_hist<<<eb, 256, 0, stream>>>(ei, CNT, RANK, E);
    k_scan_a<<<sb, 512, 0, stream>>>(CNT, ROWPTR, BSUM, DINV, N);
    k_scan_b<<<1, 128, 0, stream>>>(BSUM, sb);
    k_scan_c<<<sb, 512, 0, stream>>>(ROWPTR, BSUM, N, E);
    k_fill_csr<<<eb, 256, 0, stream>>>(ei, ROWPTR, RANK, COL, E);

    // ---- weight split / question path ----
    k_wsplit<<<(69632 + 255) / 256, 256, 0, stream>>>(W0, W1, W2, fc1w, fc2w, WTH, WTL);
    k_qq<<<N_GRAPHS, 512, 0, stream>>>(qe, fc0w, fc0b, fc1w + 128 * 128, fc1b, QQ);

    // ---- layer 1 ----
    gemm_mf<0, 0><<<gg, 128, 0, stream>>>(x, nullptr, nullptr, WTH, WTL, DINV,
                                          nullptr, nullptr, HS, nullptr, nullptr, N);
    k_gather<<<gat, 256, 0, stream>>>((const unsigned*)HS, ROWPTR, COL, DINV, b0,
                                      (unsigned*)GH, (unsigned*)GL, N);
    // ---- layer 2 ----
    gemm_mf<0, 1><<<gg, 128, 0, stream>>>(nullptr, GH, GL, WTH + 16384, WTL + 16384, DINV,
                                          nullptr, nullptr, HS, nullptr, nullptr, N);
    k_gather<<<gat, 256, 0, stream>>>((const unsigned*)HS, ROWPTR, COL, DINV, b1,
                                      (unsigned*)GH, (unsigned*)GL, N);
    // ---- layer 3 ----
    gemm_mf<0, 1><<<gg, 128, 0, stream>>>(nullptr, GH, GL, WTH + 32768, WTL + 32768, DINV,
                                          nullptr, nullptr, HS, nullptr, nullptr, N);
    k_gather<<<gat, 256, 0, stream>>>((const unsigned*)HS, ROWPTR, COL, DINV, b2,
                                      (unsigned*)GH, (unsigned*)GL, N);

    // ---- fc1 (concat folded; writes split planes) ----
    gemm_mf<1, 1><<<gg, 128, 0, stream>>>(nullptr, GH, GL, WTH + 49152, WTL + 49152, nullptr,
                                          QQ, batch, nullptr, HH, HL, N);
    // ---- fc2 -> d_out ----
    gemm_fc2<<<(N + 63) / 64, 128, 0, stream>>>(HH, HL, WTH + 65536, WTL + 65536, fc2b, out, N);
}

// Round 7
// 439.985 us; speedup vs baseline: 1.2120x; 1.0087x over previous
//
#include <hip/hip_runtime.h>
#include <hip/hip_bf16.h>

#define N_NODES 50000
#define N_EDGES 800000
#define N_GRAPHS 64

typedef __attribute__((ext_vector_type(4))) short s4v;
typedef __attribute__((ext_vector_type(8))) short s8v;
typedef __attribute__((ext_vector_type(16))) float f16v;

struct HL { short hi, lo; };

// round-to-nearest-even split of fp32 into bf16 hi + bf16 lo
__device__ inline HL bsplit(float f) {
    HL r;
    unsigned u = __float_as_uint(f);
    unsigned rh = (u + 0x7FFFu + ((u >> 16) & 1u)) >> 16;
    r.hi = (short)rh;
    float fh = __uint_as_float(rh << 16);
    float fl = f - fh;
    unsigned u2 = __float_as_uint(fl);
    unsigned rl = (u2 + 0x7FFFu + ((u2 >> 16) & 1u)) >> 16;
    r.lo = (short)rl;
    return r;
}

__device__ inline unsigned short f2bf(float f) {
    unsigned u = __float_as_uint(f);
    return (unsigned short)((u + 0x7FFFu + ((u >> 16) & 1u)) >> 16);
}

__device__ inline float bflo(unsigned u) { return __uint_as_float(u << 16); }
__device__ inline float bfhi(unsigned u) { return __uint_as_float(u & 0xFFFF0000u); }

// ---------------- degree / CSR ----------------

// hist also records each edge's rank within its dst row (coalesced write)
__global__ void k_hist(const int* __restrict__ ei, int* __restrict__ cnt,
                       int* __restrict__ rank, int E) {
    int e = blockIdx.x * 256 + threadIdx.x;
    if (e < E) rank[e] = atomicAdd(&cnt[ei[E + e]], 1);
}

// scan_a also computes dinv (fused)
__global__ __launch_bounds__(512) void k_scan_a(const int* __restrict__ cnt,
                                                int* __restrict__ rowptr,
                                                int* __restrict__ bsum,
                                                float* __restrict__ dinv, int n) {
    __shared__ int s[512];
    int t = threadIdx.x;
    int i = blockIdx.x * 512 + t;
    int v = (i < n) ? cnt[i] : 0;
    if (i < n) dinv[i] = rsqrtf((float)(v + 1));
    s[t] = v;
    __syncthreads();
    for (int d = 1; d < 512; d <<= 1) {
        int x = (t >= d) ? s[t - d] : 0;
        __syncthreads();
        s[t] += x;
        __syncthreads();
    }
    if (i < n) rowptr[i] = s[t] - v;
    if (t == 511) bsum[blockIdx.x] = s[511];
}

// merged scan_b+scan_c: every block redundantly scans the (<=128) block sums in LDS
__global__ __launch_bounds__(512) void k_scan_c(int* __restrict__ rowptr,
                                                const int* __restrict__ bsum,
                                                int n, int E, int nb) {
    __shared__ int sb[128];
    int t = threadIdx.x;
    if (t < 128) sb[t] = (t < nb) ? bsum[t] : 0;
    __syncthreads();
    for (int d = 1; d < 128; d <<= 1) {
        int x = 0;
        if (t < 128 && t >= d) x = sb[t - d];
        __syncthreads();
        if (t < 128) sb[t] += x;
        __syncthreads();
    }
    int add = (blockIdx.x > 0) ? sb[blockIdx.x - 1] : 0;
    int i = blockIdx.x * 512 + t;
    if (i < n) rowptr[i] += add;
    if (i == 0) rowptr[n] = E;
}

// no atomic: position = rowptr[dst] + rank[e]
__global__ void k_fill_csr(const int* __restrict__ ei, const int* __restrict__ rowptr,
                           const int* __restrict__ rank, int* __restrict__ colA, int E) {
    int e = blockIdx.x * 256 + threadIdx.x;
    if (e >= E) return;
    colA[rowptr[ei[E + e]] + rank[e]] = ei[e];
}

// ---------------- prep combo: qq (blocks 0..63) | wsplit (64..199) | zero CNT (200..224) ----
__global__ __launch_bounds__(512) void k_prep(const float* __restrict__ qe,
                                              const float* __restrict__ fc0w,
                                              const float* __restrict__ fc0b,
                                              const float* __restrict__ fc1w,
                                              const float* __restrict__ fc1b,
                                              const float* __restrict__ W0,
                                              const float* __restrict__ W1,
                                              const float* __restrict__ W2,
                                              const float* __restrict__ fc2w,
                                              short* __restrict__ WH,
                                              short* __restrict__ WL,
                                              int* __restrict__ cntz,
                                              float* __restrict__ qq) {
    int b = blockIdx.x, tid = threadIdx.x;
    if (b >= 200) {                       // zero CNT: 25 blocks x 512 x int4
        int idx = (b - 200) * 512 + tid;
        if (idx < 12504) ((int4*)cntz)[idx] = make_int4(0, 0, 0, 0);
        return;
    }
    if (b >= 64) {                        // weight split: 136 blocks x 512 = 69632 exact
        int i = (b - 64) * 512 + tid;
        float val;
        int dst;
        if (i < 65536) {
            int mat = i >> 14, off = i & 16383;
            int k = off >> 7, n = off & 127;
            const float* src = (mat == 0) ? W0 : (mat == 1) ? W1 : (mat == 2) ? W2 : fc1w;
            val = src[k * 128 + n];
            dst = mat * 16384 + n * 128 + k;
        } else {
            int off = i - 65536;
            int k = off >> 5, n = off & 31;
            val = fc2w[k * 32 + n];
            dst = 65536 + n * 128 + k;
        }
        HL r = bsplit(val);
        WH[dst] = r.hi;
        WL[dst] = r.lo;
        return;
    }
    // question path, graph g = b
    __shared__ float qs[768];
    __shared__ float red[512];
    __shared__ float ql[128];
    const float* fc1bot = fc1w + 128 * 128;
    int g = b;
    for (int i = tid; i < 768; i += 512) qs[i] = qe[g * 768 + i];
    __syncthreads();
    int j = tid & 127, sl = tid >> 7;
    int kb = sl * 192;
    float a0 = 0, a1 = 0, a2 = 0, a3 = 0;
    for (int k = 0; k < 192; k += 4) {
        a0 += qs[kb + k + 0] * fc0w[(kb + k + 0) * 128 + j];
        a1 += qs[kb + k + 1] * fc0w[(kb + k + 1) * 128 + j];
        a2 += qs[kb + k + 2] * fc0w[(kb + k + 2) * 128 + j];
        a3 += qs[kb + k + 3] * fc0w[(kb + k + 3) * 128 + j];
    }
    red[tid] = (a0 + a1) + (a2 + a3);
    __syncthreads();
    if (tid < 128)
        ql[tid] = fmaxf(((red[tid] + red[tid + 128]) + (red[tid + 256] + red[tid + 384]))
                        + fc0b[tid], 0.f);
    __syncthreads();
    kb = sl * 32;
    float b0 = 0, b1 = 0;
    for (int k = 0; k < 32; k += 2) {
        b0 += ql[kb + k + 0] * fc1bot[(kb + k + 0) * 128 + j];
        b1 += ql[kb + k + 1] * fc1bot[(kb + k + 1) * 128 + j];
    }
    red[tid] = b0 + b1;
    __syncthreads();
    if (tid < 128)
        qq[g * 128 + tid] = ((red[tid] + red[tid + 128]) + (red[tid + 256] + red[tid + 384]))
                            + fc1b[tid];
}

// ---------------- CSR gather over bf16 Hs, 2 feature phases, deep unroll ----------------
__global__ __launch_bounds__(256) void k_gather(const unsigned* __restrict__ Hs,
                                                const int* __restrict__ rowptr,
                                                const int* __restrict__ colA,
                                                const float* __restrict__ dinv,
                                                const float* __restrict__ bias,
                                                unsigned* __restrict__ GH,
                                                unsigned* __restrict__ GL, int n) {
    int node = __builtin_amdgcn_readfirstlane(blockIdx.x * 4 + (threadIdx.x >> 6));
    if (node >= n) return;
    int fh = blockIdx.y;                        // feature half: dwords fh*32..fh*32+31
    int lane = threadIdx.x & 63;
    int h = lane >> 5, l5 = lane & 31;
    const unsigned* base = Hs + (size_t)fh * 32 + l5;    // + s*64
    int e0 = rowptr[node], e1 = rowptr[node + 1];
    float a0 = 0.f, a1 = 0.f;
    int e = e0;
    for (; e + 16 <= e1; e += 16) {             // 8 outstanding loads per half-wave
        int s0 = colA[e + h],      s1 = colA[e + 2 + h];
        int s2 = colA[e + 4 + h],  s3 = colA[e + 6 + h];
        int s4 = colA[e + 8 + h],  s5 = colA[e + 10 + h];
        int s6 = colA[e + 12 + h], s7 = colA[e + 14 + h];
        unsigned u0 = base[(size_t)s0 * 64];
        unsigned u1 = base[(size_t)s1 * 64];
        unsigned u2 = base[(size_t)s2 * 64];
        unsigned u3 = base[(size_t)s3 * 64];
        unsigned u4 = base[(size_t)s4 * 64];
        unsigned u5 = base[(size_t)s5 * 64];
        unsigned u6 = base[(size_t)s6 * 64];
        unsigned u7 = base[(size_t)s7 * 64];
        a0 += ((bflo(u0) + bflo(u1)) + (bflo(u2) + bflo(u3)))
            + ((bflo(u4) + bflo(u5)) + (bflo(u6) + bflo(u7)));
        a1 += ((bfhi(u0) + bfhi(u1)) + (bfhi(u2) + bfhi(u3)))
            + ((bfhi(u4) + bfhi(u5)) + (bfhi(u6) + bfhi(u7)));
    }
    for (; e + 8 <= e1; e += 8) {
        int s0 = colA[e + h], s1 = colA[e + 2 + h];
        int s2 = colA[e + 4 + h], s3 = colA[e + 6 + h];
        unsigned u0 = base[(size_t)s0 * 64];
        unsigned u1 = base[(size_t)s1 * 64];
        unsigned u2 = base[(size_t)s2 * 64];
        unsigned u3 = base[(size_t)s3 * 64];
        a0 += (bflo(u0) + bflo(u1)) + (bflo(u2) + bflo(u3));
        a1 += (bfhi(u0) + bfhi(u1)) + (bfhi(u2) + bfhi(u3));
    }
    for (; e + 2 <= e1; e += 2) {
        unsigned u = base[(size_t)colA[e + h] * 64];
        a0 += bflo(u);
        a1 += bfhi(u);
    }
    if (h == 0 && e < e1) {                     // odd tail edge on half 0
        unsigned u = base[(size_t)colA[e] * 64];
        a0 += bflo(u);
        a1 += bfhi(u);
    }
    a0 += __shfl_down(a0, 32);
    a1 += __shfl_down(a1, 32);
    if (h == 0) {
        float di = dinv[node];
        unsigned uh = base[(size_t)node * 64];
        float2 bb = ((const float2*)bias)[fh * 32 + l5];
        float o0 = fmaxf((a0 + bflo(uh)) * di + bb.x, 0.f);
        float o1 = fmaxf((a1 + bfhi(uh)) * di + bb.y, 0.f);
        HL p0 = bsplit(o0), p1 = bsplit(o1);
        unsigned hp = ((unsigned)(unsigned short)p0.hi) | (((unsigned)(unsigned short)p1.hi) << 16);
        unsigned lp = ((unsigned)(unsigned short)p0.lo) | (((unsigned)(unsigned short)p1.lo) << 16);
        size_t idx = (size_t)node * 64 + fh * 32 + l5;
        GH[idx] = hp;
        GL[idx] = lp;
    }
}

// ---------------- 3xBF16-split MFMA GEMM: Hs_bf16 = (A@W)*dinv[row] ----------------
// SPLITIN 0: A fp32 (bsplit on the fly)   SPLITIN 1: A presplit bf16 planes
#define LSTR 136
template <int SPLITIN>
__global__ __launch_bounds__(128) void gemm_mf(const float* __restrict__ A32,
                                               const unsigned short* __restrict__ Ahp,
                                               const unsigned short* __restrict__ Alp,
                                               const short* __restrict__ WTh,
                                               const short* __restrict__ WTl,
                                               const float* __restrict__ dinv,
                                               unsigned short* __restrict__ oHs,
                                               int nrows) {
    __shared__ short Ah[32 * LSTR], Al[32 * LSTR];
    __shared__ short Wh[64 * LSTR], Wl[64 * LSTR];
    const int tid = threadIdx.x;
    const int row0 = blockIdx.x * 32;
    const int col0 = blockIdx.y * 64;

    if (SPLITIN == 0) {
        #pragma unroll
        for (int i = 0; i < 8; ++i) {
            int u = i * 128 + tid;
            int r = u >> 5, c4 = u & 31;
            int gr = row0 + r;
            float4 v = make_float4(0.f, 0.f, 0.f, 0.f);
            if (gr < nrows) v = ((const float4*)A32)[(size_t)gr * 32 + c4];
            HL px = bsplit(v.x), py = bsplit(v.y), pz = bsplit(v.z), pw = bsplit(v.w);
            s4v h4 = {px.hi, py.hi, pz.hi, pw.hi};
            s4v l4 = {px.lo, py.lo, pz.lo, pw.lo};
            *(s4v*)&Ah[r * LSTR + c4 * 4] = h4;
            *(s4v*)&Al[r * LSTR + c4 * 4] = l4;
        }
    } else {
        #pragma unroll
        for (int i = 0; i < 4; ++i) {
            int u = i * 128 + tid;
            int r = u >> 4, j = u & 15;
            int gr = row0 + r;
            s8v h8 = {}, l8 = {};
            if (gr < nrows) {
                h8 = *(const s8v*)&Ahp[(size_t)gr * 128 + j * 8];
                l8 = *(const s8v*)&Alp[(size_t)gr * 128 + j * 8];
            }
            *(s8v*)&Ah[r * LSTR + j * 8] = h8;
            *(s8v*)&Al[r * LSTR + j * 8] = l8;
        }
    }
    #pragma unroll
    for (int i = 0; i < 8; ++i) {
        int u = i * 128 + tid;
        int c = u >> 4, j = u & 15;
        *(s8v*)&Wh[c * LSTR + j * 8] = *(const s8v*)&WTh[(size_t)(col0 + c) * 128 + j * 8];
        *(s8v*)&Wl[c * LSTR + j * 8] = *(const s8v*)&WTl[(size_t)(col0 + c) * 128 + j * 8];
    }
    __syncthreads();

    const int wv = tid >> 6, lane = tid & 63;
    const int m = lane & 31, half = lane >> 5;
    const int colb = wv * 32;
    f16v acc = {0.f};
    #pragma unroll
    for (int ks = 0; ks < 8; ++ks) {
        int ko = ks * 16 + half * 8;
        s8v ah = *(const s8v*)&Ah[m * LSTR + ko];
        s8v al = *(const s8v*)&Al[m * LSTR + ko];
        s8v bh = *(const s8v*)&Wh[(colb + m) * LSTR + ko];
        s8v bl = *(const s8v*)&Wl[(colb + m) * LSTR + ko];
        acc = __builtin_amdgcn_mfma_f32_32x32x16_bf16(ah, bh, acc, 0, 0, 0);
        acc = __builtin_amdgcn_mfma_f32_32x32x16_bf16(ah, bl, acc, 0, 0, 0);
        acc = __builtin_amdgcn_mfma_f32_32x32x16_bf16(al, bh, acc, 0, 0, 0);
    }

    #pragma unroll
    for (int reg = 0; reg < 16; ++reg) {
        int rl = (reg & 3) + 8 * (reg >> 2) + 4 * half;
        int gr = row0 + rl;
        if (gr >= nrows) continue;
        int gc = col0 + colb + m;
        oHs[(size_t)gr * 128 + gc] = f2bf(acc[reg] * dinv[gr]);
    }
}

// ---------------- fused fc1+fc2: d_out[32x32] per block ----------------
// Stage 1: C1(32x128) = A(32x128)@fc1top, relu(+qq[batch]), split -> LDS planes (reuse Ah/Al)
// Stage 2: out(32x32) = P(32x128)@fc2w, split-K across the 2 waves, LDS-reduce.
__global__ __launch_bounds__(128) void k_fc12(const unsigned short* __restrict__ Ahp,
                                              const unsigned short* __restrict__ Alp,
                                              const short* __restrict__ W1h,
                                              const short* __restrict__ W1l,
                                              const short* __restrict__ W2h,
                                              const short* __restrict__ W2l,
                                              const float* __restrict__ qq,
                                              const int* __restrict__ batch,
                                              const float* __restrict__ bias,
                                              float* __restrict__ out, int nrows) {
    __shared__ short Ah[32 * LSTR], Al[32 * LSTR];
    __shared__ short Wh[128 * LSTR], Wl[128 * LSTR];
    __shared__ float red[32 * 33];
    const int tid = threadIdx.x;
    const int row0 = blockIdx.x * 32;

    #pragma unroll
    for (int i = 0; i < 4; ++i) {              // A: 32 rows x 16 s8v (both planes)
        int u = i * 128 + tid;
        int r = u >> 4, j = u & 15;
        int gr = row0 + r;
        s8v h8 = {}, l8 = {};
        if (gr < nrows) {
            h8 = *(const s8v*)&Ahp[(size_t)gr * 128 + j * 8];
            l8 = *(const s8v*)&Alp[(size_t)gr * 128 + j * 8];
        }
        *(s8v*)&Ah[r * LSTR + j * 8] = h8;
        *(s8v*)&Al[r * LSTR + j * 8] = l8;
    }
    #pragma unroll
    for (int i = 0; i < 16; ++i) {             // W1: 128 cols x 16 s8v
        int u = i * 128 + tid;
        int c = u >> 4, j = u & 15;
        *(s8v*)&Wh[c * LSTR + j * 8] = *(const s8v*)&W1h[(size_t)c * 128 + j * 8];
        *(s8v*)&Wl[c * LSTR + j * 8] = *(const s8v*)&W1l[(size_t)c * 128 + j * 8];
    }
    __syncthreads();

    const int wv = tid >> 6, lane = tid & 63;
    const int m = lane & 31, half = lane >> 5;
    f16v acc0 = {0.f}, acc1 = {0.f};           // cols wv*64+m, wv*64+32+m
    #pragma unroll
    for (int ks = 0; ks < 8; ++ks) {
        int ko = ks * 16 + half * 8;
        s8v ah = *(const s8v*)&Ah[m * LSTR + ko];
        s8v al = *(const s8v*)&Al[m * LSTR + ko];
        int c0 = wv * 64 + m;
        s8v bh0 = *(const s8v*)&Wh[c0 * LSTR + ko];
        s8v bl0 = *(const s8v*)&Wl[c0 * LSTR + ko];
        s8v bh1 = *(const s8v*)&Wh[(c0 + 32) * LSTR + ko];
        s8v bl1 = *(const s8v*)&Wl[(c0 + 32) * LSTR + ko];
        acc0 = __builtin_amdgcn_mfma_f32_32x32x16_bf16(ah, bh0, acc0, 0, 0, 0);
        acc0 = __builtin_amdgcn_mfma_f32_32x32x16_bf16(ah, bl0, acc0, 0, 0, 0);
        acc0 = __builtin_amdgcn_mfma_f32_32x32x16_bf16(al, bh0, acc0, 0, 0, 0);
        acc1 = __builtin_amdgcn_mfma_f32_32x32x16_bf16(ah, bh1, acc1, 0, 0, 0);
        acc1 = __builtin_amdgcn_mfma_f32_32x32x16_bf16(ah, bl1, acc1, 0, 0, 0);
        acc1 = __builtin_amdgcn_mfma_f32_32x32x16_bf16(al, bh1, acc1, 0, 0, 0);
    }
    __syncthreads();                            // done reading Ah/Al

    // epilogue: relu(+qq), split, write P planes into Ah/Al
    #pragma unroll
    for (int reg = 0; reg < 16; ++reg) {
        int rl = (reg & 3) + 8 * (reg >> 2) + 4 * half;
        int gr = row0 + rl;
        int g = (gr < nrows) ? batch[gr] : 0;
        float q0 = qq[(size_t)g * 128 + wv * 64 + m];
        float q1 = qq[(size_t)g * 128 + wv * 64 + 32 + m];
        float v0 = fmaxf(acc0[reg] + q0, 0.f);
        float v1 = fmaxf(acc1[reg] + q1, 0.f);
        HL p0 = bsplit(v0), p1 = bsplit(v1);
        Ah[rl * LSTR + wv * 64 + m] = p0.hi;
        Al[rl * LSTR + wv * 64 + m] = p0.lo;
        Ah[rl * LSTR + wv * 64 + 32 + m] = p1.hi;
        Al[rl * LSTR + wv * 64 + 32 + m] = p1.lo;
    }
    __syncthreads();

    // stage 2: split-K (wave wv handles k in [wv*64, wv*64+64))
    f16v acc2 = {0.f};
    #pragma unroll
    for (int ks = 0; ks < 4; ++ks) {
        int ko = wv * 64 + ks * 16 + half * 8;
        s8v ah = *(const s8v*)&Ah[m * LSTR + ko];
        s8v al = *(const s8v*)&Al[m * LSTR + ko];
        s8v bh = *(const s8v*)&W2h[(size_t)m * 128 + ko];
        s8v bl = *(const s8v*)&W2l[(size_t)m * 128 + ko];
        acc2 = __builtin_amdgcn_mfma_f32_32x32x16_bf16(ah, bh, acc2, 0, 0, 0);
        acc2 = __builtin_amdgcn_mfma_f32_32x32x16_bf16(ah, bl, acc2, 0, 0, 0);
        acc2 = __builtin_amdgcn_mfma_f32_32x32x16_bf16(al, bh, acc2, 0, 0, 0);
    }
    if (wv == 1) {
        #pragma unroll
        for (int reg = 0; reg < 16; ++reg) {
            int rl = (reg & 3) + 8 * (reg >> 2) + 4 * half;
            red[rl * 33 + m] = acc2[reg];
        }
    }
    __syncthreads();
    if (wv == 0) {
        #pragma unroll
        for (int reg = 0; reg < 16; ++reg) {
            int rl = (reg & 3) + 8 * (reg >> 2) + 4 * half;
            int gr = row0 + rl;
            if (gr < nrows)
                out[(size_t)gr * 32 + m] = acc2[reg] + red[rl * 33 + m] + bias[m];
        }
    }
}

// ---------------- launch ----------------

extern "C" void kernel_launch(void* const* d_in, const int* in_sizes, int n_in,
                              void* d_out, int out_size, void* d_ws, size_t ws_size,
                              hipStream_t stream) {
    const float* x    = (const float*)d_in[0];
    const int*   ei   = (const int*)d_in[1];
    const int*   batch= (const int*)d_in[2];
    const float* qe   = (const float*)d_in[3];
    const float* W0   = (const float*)d_in[4];
    const float* b0   = (const float*)d_in[5];
    const float* W1   = (const float*)d_in[6];
    const float* b1   = (const float*)d_in[7];
    const float* W2   = (const float*)d_in[8];
    const float* b2   = (const float*)d_in[9];
    const float* fc0w = (const float*)d_in[10];
    const float* fc0b = (const float*)d_in[11];
    const float* fc1w = (const float*)d_in[12];
    const float* fc1b = (const float*)d_in[13];
    const float* fc2w = (const float*)d_in[14];
    const float* fc2b = (const float*)d_in[15];
    float* out = (float*)d_out;

    float* WS = (float*)d_ws;
    unsigned short* HS = (unsigned short*)WS;             // bf16 [50000,128]
    unsigned short* GH = (unsigned short*)(WS + 3200000); // bf16 hi plane
    unsigned short* GL = (unsigned short*)(WS + 6400000); // bf16 lo plane
    float* DINV = WS + 12800000;             // [50016]
    float* QQ   = WS + 12850016;             // [8192]
    int*   CNT  = (int*)(WS + 12858208);     // [50016]
    int*   ROWPTR = (int*)(WS + 12908224);   // [50016]
    int*   RANK = (int*)(WS + 12958240);     // [800000]
    int*   COL  = (int*)(WS + 13758240);     // [800000]
    int*   BSUM = (int*)(WS + 14558240);     // [128]
    short* WTH  = (short*)(WS + 14558368);   // [69632]
    short* WTL  = WTH + 69632;               // [69632]

    const int N = N_NODES, E = N_EDGES;
    const int eb = (E + 255) / 256;
    const int sb = (N + 511) / 512;          // 98
    const dim3 gg((N + 31) / 32, 2);
    const dim3 gat((N + 3) / 4, 2);

    // ---- prep (zero CNT + weight split + question path) ----
    k_prep<<<225, 512, 0, stream>>>(qe, fc0w, fc0b, fc1w, fc1b, W0, W1, W2, fc2w,
                                    WTH, WTL, CNT, QQ);
    // ---- CSR build ----
    k_hist<<<eb, 256, 0, stream>>>(ei, CNT, RANK, E);
    k_scan_a<<<sb, 512, 0, stream>>>(CNT, ROWPTR, BSUM, DINV, N);
    k_scan_c<<<sb, 512, 0, stream>>>(ROWPTR, BSUM, N, E, sb);
    k_fill_csr<<<eb, 256, 0, stream>>>(ei, ROWPTR, RANK, COL, E);

    // ---- layer 1 ----
    gemm_mf<0><<<gg, 128, 0, stream>>>(x, nullptr, nullptr, WTH, WTL, DINV, HS, N);
    k_gather<<<gat, 256, 0, stream>>>((const unsigned*)HS, ROWPTR, COL, DINV, b0,
                                      (unsigned*)GH, (unsigned*)GL, N);
    // ---- layer 2 ----
    gemm_mf<1><<<gg, 128, 0, stream>>>(nullptr, GH, GL, WTH + 16384, WTL + 16384, DINV, HS, N);
    k_gather<<<gat, 256, 0, stream>>>((const unsigned*)HS, ROWPTR, COL, DINV, b1,
                                      (unsigned*)GH, (unsigned*)GL, N);
    // ---- layer 3 ----
    gemm_mf<1><<<gg, 128, 0, stream>>>(nullptr, GH, GL, WTH + 32768, WTL + 32768, DINV, HS, N);
    k_gather<<<gat, 256, 0, stream>>>((const unsigned*)HS, ROWPTR, COL, DINV, b2,
                                      (unsigned*)GH, (unsigned*)GL, N);

    // ---- fused fc1 + fc2 -> d_out ----
    k_fc12<<<(N + 31) / 32, 128, 0, stream>>>(GH, GL, WTH + 49152, WTL + 49152,
                                              WTH + 65536, WTL + 65536,
                                              QQ, batch, fc2b, out, N);
}

// Round 8
// 408.330 us; speedup vs baseline: 1.3060x; 1.0775x over previous
//
#include <hip/hip_runtime.h>
#include <hip/hip_bf16.h>

#define N_NODES 50000
#define N_EDGES 800000
#define N_GRAPHS 64

typedef __attribute__((ext_vector_type(4))) short s4v;
typedef __attribute__((ext_vector_type(8))) short s8v;
typedef __attribute__((ext_vector_type(16))) float f16v;

struct HL { short hi, lo; };

// round-to-nearest-even split of fp32 into bf16 hi + bf16 lo
__device__ inline HL bsplit(float f) {
    HL r;
    unsigned u = __float_as_uint(f);
    unsigned rh = (u + 0x7FFFu + ((u >> 16) & 1u)) >> 16;
    r.hi = (short)rh;
    float fh = __uint_as_float(rh << 16);
    float fl = f - fh;
    unsigned u2 = __float_as_uint(fl);
    unsigned rl = (u2 + 0x7FFFu + ((u2 >> 16) & 1u)) >> 16;
    r.lo = (short)rl;
    return r;
}

__device__ inline unsigned short f2bf(float f) {
    unsigned u = __float_as_uint(f);
    return (unsigned short)((u + 0x7FFFu + ((u >> 16) & 1u)) >> 16);
}

__device__ inline float bflo(unsigned u) { return __uint_as_float(u << 16); }
__device__ inline float bfhi(unsigned u) { return __uint_as_float(u & 0xFFFF0000u); }

// ---------------- degree / CSR ----------------

// hist also records each edge's rank within its dst row (coalesced write)
__global__ void k_hist(const int* __restrict__ ei, int* __restrict__ cnt,
                       int* __restrict__ rank, int E) {
    int e = blockIdx.x * 256 + threadIdx.x;
    if (e < E) rank[e] = atomicAdd(&cnt[ei[E + e]], 1);
}

// scan_a also computes dinv (fused)
__global__ __launch_bounds__(512) void k_scan_a(const int* __restrict__ cnt,
                                                int* __restrict__ rowptr,
                                                int* __restrict__ bsum,
                                                float* __restrict__ dinv, int n) {
    __shared__ int s[512];
    int t = threadIdx.x;
    int i = blockIdx.x * 512 + t;
    int v = (i < n) ? cnt[i] : 0;
    if (i < n) dinv[i] = rsqrtf((float)(v + 1));
    s[t] = v;
    __syncthreads();
    for (int d = 1; d < 512; d <<= 1) {
        int x = (t >= d) ? s[t - d] : 0;
        __syncthreads();
        s[t] += x;
        __syncthreads();
    }
    if (i < n) rowptr[i] = s[t] - v;
    if (t == 511) bsum[blockIdx.x] = s[511];
}

// merged scan_b+scan_c: every block redundantly scans the (<=128) block sums in LDS
__global__ __launch_bounds__(512) void k_scan_c(int* __restrict__ rowptr,
                                                const int* __restrict__ bsum,
                                                int n, int E, int nb) {
    __shared__ int sb[128];
    int t = threadIdx.x;
    if (t < 128) sb[t] = (t < nb) ? bsum[t] : 0;
    __syncthreads();
    for (int d = 1; d < 128; d <<= 1) {
        int x = 0;
        if (t < 128 && t >= d) x = sb[t - d];
        __syncthreads();
        if (t < 128) sb[t] += x;
        __syncthreads();
    }
    int add = (blockIdx.x > 0) ? sb[blockIdx.x - 1] : 0;
    int i = blockIdx.x * 512 + t;
    if (i < n) rowptr[i] += add;
    if (i == 0) rowptr[n] = E;
}

// no atomic: position = rowptr[dst] + rank[e]
__global__ void k_fill_csr(const int* __restrict__ ei, const int* __restrict__ rowptr,
                           const int* __restrict__ rank, int* __restrict__ colA, int E) {
    int e = blockIdx.x * 256 + threadIdx.x;
    if (e >= E) return;
    colA[rowptr[ei[E + e]] + rank[e]] = ei[e];
}

// ---------------- prep combo: qq (blocks 0..63) | wsplit (64..199) | zero CNT (200..224) ----
__global__ __launch_bounds__(512) void k_prep(const float* __restrict__ qe,
                                              const float* __restrict__ fc0w,
                                              const float* __restrict__ fc0b,
                                              const float* __restrict__ fc1w,
                                              const float* __restrict__ fc1b,
                                              const float* __restrict__ W0,
                                              const float* __restrict__ W1,
                                              const float* __restrict__ W2,
                                              const float* __restrict__ fc2w,
                                              short* __restrict__ WH,
                                              short* __restrict__ WL,
                                              int* __restrict__ cntz,
                                              float* __restrict__ qq) {
    int b = blockIdx.x, tid = threadIdx.x;
    if (b >= 200) {                       // zero CNT: 25 blocks x 512 x int4
        int idx = (b - 200) * 512 + tid;
        if (idx < 12504) ((int4*)cntz)[idx] = make_int4(0, 0, 0, 0);
        return;
    }
    if (b >= 64) {                        // weight split: 136 blocks x 512 = 69632 exact
        int i = (b - 64) * 512 + tid;
        float val;
        int dst;
        if (i < 65536) {
            int mat = i >> 14, off = i & 16383;
            int k = off >> 7, n = off & 127;
            const float* src = (mat == 0) ? W0 : (mat == 1) ? W1 : (mat == 2) ? W2 : fc1w;
            val = src[k * 128 + n];
            dst = mat * 16384 + n * 128 + k;
        } else {
            int off = i - 65536;
            int k = off >> 5, n = off & 31;
            val = fc2w[k * 32 + n];
            dst = 65536 + n * 128 + k;
        }
        HL r = bsplit(val);
        WH[dst] = r.hi;
        WL[dst] = r.lo;
        return;
    }
    // question path, graph g = b
    __shared__ float qs[768];
    __shared__ float red[512];
    __shared__ float ql[128];
    const float* fc1bot = fc1w + 128 * 128;
    int g = b;
    for (int i = tid; i < 768; i += 512) qs[i] = qe[g * 768 + i];
    __syncthreads();
    int j = tid & 127, sl = tid >> 7;
    int kb = sl * 192;
    float a0 = 0, a1 = 0, a2 = 0, a3 = 0;
    for (int k = 0; k < 192; k += 4) {
        a0 += qs[kb + k + 0] * fc0w[(kb + k + 0) * 128 + j];
        a1 += qs[kb + k + 1] * fc0w[(kb + k + 1) * 128 + j];
        a2 += qs[kb + k + 2] * fc0w[(kb + k + 2) * 128 + j];
        a3 += qs[kb + k + 3] * fc0w[(kb + k + 3) * 128 + j];
    }
    red[tid] = (a0 + a1) + (a2 + a3);
    __syncthreads();
    if (tid < 128)
        ql[tid] = fmaxf(((red[tid] + red[tid + 128]) + (red[tid + 256] + red[tid + 384]))
                        + fc0b[tid], 0.f);
    __syncthreads();
    kb = sl * 32;
    float b0 = 0, b1 = 0;
    for (int k = 0; k < 32; k += 2) {
        b0 += ql[kb + k + 0] * fc1bot[(kb + k + 0) * 128 + j];
        b1 += ql[kb + k + 1] * fc1bot[(kb + k + 1) * 128 + j];
    }
    red[tid] = b0 + b1;
    __syncthreads();
    if (tid < 128)
        qq[g * 128 + tid] = ((red[tid] + red[tid + 128]) + (red[tid + 256] + red[tid + 384]))
                            + fc1b[tid];
}

// ---------------- CSR gather over bf16 Hs, 2 feature phases, deep unroll ----------------
__global__ __launch_bounds__(256) void k_gather(const unsigned* __restrict__ Hs,
                                                const int* __restrict__ rowptr,
                                                const int* __restrict__ colA,
                                                const float* __restrict__ dinv,
                                                const float* __restrict__ bias,
                                                unsigned* __restrict__ GH,
                                                unsigned* __restrict__ GL, int n) {
    int node = __builtin_amdgcn_readfirstlane(blockIdx.x * 4 + (threadIdx.x >> 6));
    if (node >= n) return;
    int fh = blockIdx.y;                        // feature half: dwords fh*32..fh*32+31
    int lane = threadIdx.x & 63;
    int h = lane >> 5, l5 = lane & 31;
    const unsigned* base = Hs + (size_t)fh * 32 + l5;    // + s*64
    int e0 = rowptr[node], e1 = rowptr[node + 1];
    float a0 = 0.f, a1 = 0.f;
    int e = e0;
    for (; e + 16 <= e1; e += 16) {             // 8 outstanding loads per half-wave
        int s0 = colA[e + h],      s1 = colA[e + 2 + h];
        int s2 = colA[e + 4 + h],  s3 = colA[e + 6 + h];
        int s4 = colA[e + 8 + h],  s5 = colA[e + 10 + h];
        int s6 = colA[e + 12 + h], s7 = colA[e + 14 + h];
        unsigned u0 = base[(size_t)s0 * 64];
        unsigned u1 = base[(size_t)s1 * 64];
        unsigned u2 = base[(size_t)s2 * 64];
        unsigned u3 = base[(size_t)s3 * 64];
        unsigned u4 = base[(size_t)s4 * 64];
        unsigned u5 = base[(size_t)s5 * 64];
        unsigned u6 = base[(size_t)s6 * 64];
        unsigned u7 = base[(size_t)s7 * 64];
        a0 += ((bflo(u0) + bflo(u1)) + (bflo(u2) + bflo(u3)))
            + ((bflo(u4) + bflo(u5)) + (bflo(u6) + bflo(u7)));
        a1 += ((bfhi(u0) + bfhi(u1)) + (bfhi(u2) + bfhi(u3)))
            + ((bfhi(u4) + bfhi(u5)) + (bfhi(u6) + bfhi(u7)));
    }
    for (; e + 8 <= e1; e += 8) {
        int s0 = colA[e + h], s1 = colA[e + 2 + h];
        int s2 = colA[e + 4 + h], s3 = colA[e + 6 + h];
        unsigned u0 = base[(size_t)s0 * 64];
        unsigned u1 = base[(size_t)s1 * 64];
        unsigned u2 = base[(size_t)s2 * 64];
        unsigned u3 = base[(size_t)s3 * 64];
        a0 += (bflo(u0) + bflo(u1)) + (bflo(u2) + bflo(u3));
        a1 += (bfhi(u0) + bfhi(u1)) + (bfhi(u2) + bfhi(u3));
    }
    for (; e + 2 <= e1; e += 2) {
        unsigned u = base[(size_t)colA[e + h] * 64];
        a0 += bflo(u);
        a1 += bfhi(u);
    }
    if (h == 0 && e < e1) {                     // odd tail edge on half 0
        unsigned u = base[(size_t)colA[e] * 64];
        a0 += bflo(u);
        a1 += bfhi(u);
    }
    a0 += __shfl_down(a0, 32);
    a1 += __shfl_down(a1, 32);
    if (h == 0) {
        float di = dinv[node];
        unsigned uh = base[(size_t)node * 64];
        float2 bb = ((const float2*)bias)[fh * 32 + l5];
        float o0 = fmaxf((a0 + bflo(uh)) * di + bb.x, 0.f);
        float o1 = fmaxf((a1 + bfhi(uh)) * di + bb.y, 0.f);
        HL p0 = bsplit(o0), p1 = bsplit(o1);
        unsigned hp = ((unsigned)(unsigned short)p0.hi) | (((unsigned)(unsigned short)p1.hi) << 16);
        unsigned lp = ((unsigned)(unsigned short)p0.lo) | (((unsigned)(unsigned short)p1.lo) << 16);
        size_t idx = (size_t)node * 64 + fh * 32 + l5;
        GH[idx] = hp;
        GL[idx] = lp;
    }
}

// ---------------- 3xBF16-split MFMA GEMM: Hs_bf16 = (A@W)*dinv[row] ----------------
// SPLITIN 0: A fp32 (bsplit on the fly)   SPLITIN 1: A presplit bf16 planes
#define LSTR 136
template <int SPLITIN>
__global__ __launch_bounds__(128) void gemm_mf(const float* __restrict__ A32,
                                               const unsigned short* __restrict__ Ahp,
                                               const unsigned short* __restrict__ Alp,
                                               const short* __restrict__ WTh,
                                               const short* __restrict__ WTl,
                                               const float* __restrict__ dinv,
                                               unsigned short* __restrict__ oHs,
                                               int nrows) {
    __shared__ short Ah[32 * LSTR], Al[32 * LSTR];
    __shared__ short Wh[64 * LSTR], Wl[64 * LSTR];
    const int tid = threadIdx.x;
    const int row0 = blockIdx.x * 32;
    const int col0 = blockIdx.y * 64;

    if (SPLITIN == 0) {
        #pragma unroll
        for (int i = 0; i < 8; ++i) {
            int u = i * 128 + tid;
            int r = u >> 5, c4 = u & 31;
            int gr = row0 + r;
            float4 v = make_float4(0.f, 0.f, 0.f, 0.f);
            if (gr < nrows) v = ((const float4*)A32)[(size_t)gr * 32 + c4];
            HL px = bsplit(v.x), py = bsplit(v.y), pz = bsplit(v.z), pw = bsplit(v.w);
            s4v h4 = {px.hi, py.hi, pz.hi, pw.hi};
            s4v l4 = {px.lo, py.lo, pz.lo, pw.lo};
            *(s4v*)&Ah[r * LSTR + c4 * 4] = h4;
            *(s4v*)&Al[r * LSTR + c4 * 4] = l4;
        }
    } else {
        #pragma unroll
        for (int i = 0; i < 4; ++i) {
            int u = i * 128 + tid;
            int r = u >> 4, j = u & 15;
            int gr = row0 + r;
            s8v h8 = {}, l8 = {};
            if (gr < nrows) {
                h8 = *(const s8v*)&Ahp[(size_t)gr * 128 + j * 8];
                l8 = *(const s8v*)&Alp[(size_t)gr * 128 + j * 8];
            }
            *(s8v*)&Ah[r * LSTR + j * 8] = h8;
            *(s8v*)&Al[r * LSTR + j * 8] = l8;
        }
    }
    #pragma unroll
    for (int i = 0; i < 8; ++i) {
        int u = i * 128 + tid;
        int c = u >> 4, j = u & 15;
        *(s8v*)&Wh[c * LSTR + j * 8] = *(const s8v*)&WTh[(size_t)(col0 + c) * 128 + j * 8];
        *(s8v*)&Wl[c * LSTR + j * 8] = *(const s8v*)&WTl[(size_t)(col0 + c) * 128 + j * 8];
    }
    __syncthreads();

    const int wv = tid >> 6, lane = tid & 63;
    const int m = lane & 31, half = lane >> 5;
    const int colb = wv * 32;
    f16v acc = {0.f};
    #pragma unroll
    for (int ks = 0; ks < 8; ++ks) {
        int ko = ks * 16 + half * 8;
        s8v ah = *(const s8v*)&Ah[m * LSTR + ko];
        s8v al = *(const s8v*)&Al[m * LSTR + ko];
        s8v bh = *(const s8v*)&Wh[(colb + m) * LSTR + ko];
        s8v bl = *(const s8v*)&Wl[(colb + m) * LSTR + ko];
        acc = __builtin_amdgcn_mfma_f32_32x32x16_bf16(ah, bh, acc, 0, 0, 0);
        acc = __builtin_amdgcn_mfma_f32_32x32x16_bf16(ah, bl, acc, 0, 0, 0);
        acc = __builtin_amdgcn_mfma_f32_32x32x16_bf16(al, bh, acc, 0, 0, 0);
    }

    #pragma unroll
    for (int reg = 0; reg < 16; ++reg) {
        int rl = (reg & 3) + 8 * (reg >> 2) + 4 * half;
        int gr = row0 + rl;
        if (gr >= nrows) continue;
        int gc = col0 + colb + m;
        oHs[(size_t)gr * 128 + gc] = f2bf(acc[reg] * dinv[gr]);
    }
}

// ---------------- fused fc1+fc2: d_out[32x32] per block ----------------
// W1/W2 fragments read straight from global (L1/L2-cached, shared across blocks);
// LDS only holds the 32-row A/P planes + reduce buffer (~21.6 KB -> high occupancy).
__global__ __launch_bounds__(128) void k_fc12(const unsigned short* __restrict__ Ahp,
                                              const unsigned short* __restrict__ Alp,
                                              const short* __restrict__ W1h,
                                              const short* __restrict__ W1l,
                                              const short* __restrict__ W2h,
                                              const short* __restrict__ W2l,
                                              const float* __restrict__ qq,
                                              const int* __restrict__ batch,
                                              const float* __restrict__ bias,
                                              float* __restrict__ out, int nrows) {
    __shared__ short Ah[32 * LSTR], Al[32 * LSTR];
    __shared__ float red[32 * 33];
    const int tid = threadIdx.x;
    const int row0 = blockIdx.x * 32;

    #pragma unroll
    for (int i = 0; i < 4; ++i) {              // A: 32 rows x 16 s8v (both planes)
        int u = i * 128 + tid;
        int r = u >> 4, j = u & 15;
        int gr = row0 + r;
        s8v h8 = {}, l8 = {};
        if (gr < nrows) {
            h8 = *(const s8v*)&Ahp[(size_t)gr * 128 + j * 8];
            l8 = *(const s8v*)&Alp[(size_t)gr * 128 + j * 8];
        }
        *(s8v*)&Ah[r * LSTR + j * 8] = h8;
        *(s8v*)&Al[r * LSTR + j * 8] = l8;
    }
    __syncthreads();

    const int wv = tid >> 6, lane = tid & 63;
    const int m = lane & 31, half = lane >> 5;
    f16v acc0 = {0.f}, acc1 = {0.f};           // cols wv*64+m, wv*64+32+m
    const int c0 = wv * 64 + m;
    #pragma unroll
    for (int ks = 0; ks < 8; ++ks) {
        int ko = ks * 16 + half * 8;
        s8v ah = *(const s8v*)&Ah[m * LSTR + ko];
        s8v al = *(const s8v*)&Al[m * LSTR + ko];
        s8v bh0 = *(const s8v*)&W1h[(size_t)c0 * 128 + ko];
        s8v bl0 = *(const s8v*)&W1l[(size_t)c0 * 128 + ko];
        s8v bh1 = *(const s8v*)&W1h[(size_t)(c0 + 32) * 128 + ko];
        s8v bl1 = *(const s8v*)&W1l[(size_t)(c0 + 32) * 128 + ko];
        acc0 = __builtin_amdgcn_mfma_f32_32x32x16_bf16(ah, bh0, acc0, 0, 0, 0);
        acc0 = __builtin_amdgcn_mfma_f32_32x32x16_bf16(ah, bl0, acc0, 0, 0, 0);
        acc0 = __builtin_amdgcn_mfma_f32_32x32x16_bf16(al, bh0, acc0, 0, 0, 0);
        acc1 = __builtin_amdgcn_mfma_f32_32x32x16_bf16(ah, bh1, acc1, 0, 0, 0);
        acc1 = __builtin_amdgcn_mfma_f32_32x32x16_bf16(ah, bl1, acc1, 0, 0, 0);
        acc1 = __builtin_amdgcn_mfma_f32_32x32x16_bf16(al, bh1, acc1, 0, 0, 0);
    }
    __syncthreads();                            // done reading Ah/Al

    // epilogue: relu(+qq), split, write P planes into Ah/Al
    #pragma unroll
    for (int reg = 0; reg < 16; ++reg) {
        int rl = (reg & 3) + 8 * (reg >> 2) + 4 * half;
        int gr = row0 + rl;
        int g = (gr < nrows) ? batch[gr] : 0;
        float q0 = qq[(size_t)g * 128 + wv * 64 + m];
        float q1 = qq[(size_t)g * 128 + wv * 64 + 32 + m];
        float v0 = fmaxf(acc0[reg] + q0, 0.f);
        float v1 = fmaxf(acc1[reg] + q1, 0.f);
        HL p0 = bsplit(v0), p1 = bsplit(v1);
        Ah[rl * LSTR + wv * 64 + m] = p0.hi;
        Al[rl * LSTR + wv * 64 + m] = p0.lo;
        Ah[rl * LSTR + wv * 64 + 32 + m] = p1.hi;
        Al[rl * LSTR + wv * 64 + 32 + m] = p1.lo;
    }
    __syncthreads();

    // stage 2: split-K (wave wv handles k in [wv*64, wv*64+64))
    f16v acc2 = {0.f};
    #pragma unroll
    for (int ks = 0; ks < 4; ++ks) {
        int ko = wv * 64 + ks * 16 + half * 8;
        s8v ah = *(const s8v*)&Ah[m * LSTR + ko];
        s8v al = *(const s8v*)&Al[m * LSTR + ko];
        s8v bh = *(const s8v*)&W2h[(size_t)m * 128 + ko];
        s8v bl = *(const s8v*)&W2l[(size_t)m * 128 + ko];
        acc2 = __builtin_amdgcn_mfma_f32_32x32x16_bf16(ah, bh, acc2, 0, 0, 0);
        acc2 = __builtin_amdgcn_mfma_f32_32x32x16_bf16(ah, bl, acc2, 0, 0, 0);
        acc2 = __builtin_amdgcn_mfma_f32_32x32x16_bf16(al, bh, acc2, 0, 0, 0);
    }
    if (wv == 1) {
        #pragma unroll
        for (int reg = 0; reg < 16; ++reg) {
            int rl = (reg & 3) + 8 * (reg >> 2) + 4 * half;
            red[rl * 33 + m] = acc2[reg];
        }
    }
    __syncthreads();
    if (wv == 0) {
        #pragma unroll
        for (int reg = 0; reg < 16; ++reg) {
            int rl = (reg & 3) + 8 * (reg >> 2) + 4 * half;
            int gr = row0 + rl;
            if (gr < nrows)
                out[(size_t)gr * 32 + m] = acc2[reg] + red[rl * 33 + m] + bias[m];
        }
    }
}

// ---------------- launch ----------------

extern "C" void kernel_launch(void* const* d_in, const int* in_sizes, int n_in,
                              void* d_out, int out_size, void* d_ws, size_t ws_size,
                              hipStream_t stream) {
    const float* x    = (const float*)d_in[0];
    const int*   ei   = (const int*)d_in[1];
    const int*   batch= (const int*)d_in[2];
    const float* qe   = (const float*)d_in[3];
    const float* W0   = (const float*)d_in[4];
    const float* b0   = (const float*)d_in[5];
    const float* W1   = (const float*)d_in[6];
    const float* b1   = (const float*)d_in[7];
    const float* W2   = (const float*)d_in[8];
    const float* b2   = (const float*)d_in[9];
    const float* fc0w = (const float*)d_in[10];
    const float* fc0b = (const float*)d_in[11];
    const float* fc1w = (const float*)d_in[12];
    const float* fc1b = (const float*)d_in[13];
    const float* fc2w = (const float*)d_in[14];
    const float* fc2b = (const float*)d_in[15];
    float* out = (float*)d_out;

    float* WS = (float*)d_ws;
    unsigned short* HS = (unsigned short*)WS;             // bf16 [50000,128]
    unsigned short* GH = (unsigned short*)(WS + 3200000); // bf16 hi plane
    unsigned short* GL = (unsigned short*)(WS + 6400000); // bf16 lo plane
    float* DINV = WS + 12800000;             // [50016]
    float* QQ   = WS + 12850016;             // [8192]
    int*   CNT  = (int*)(WS + 12858208);     // [50016]
    int*   ROWPTR = (int*)(WS + 12908224);   // [50016]
    int*   RANK = (int*)(WS + 12958240);     // [800000]
    int*   COL  = (int*)(WS + 13758240);     // [800000]
    int*   BSUM = (int*)(WS + 14558240);     // [128]
    short* WTH  = (short*)(WS + 14558368);   // [69632]
    short* WTL  = WTH + 69632;               // [69632]

    const int N = N_NODES, E = N_EDGES;
    const int eb = (E + 255) / 256;
    const int sb = (N + 511) / 512;          // 98
    const dim3 gg((N + 31) / 32, 2);
    const dim3 gat((N + 3) / 4, 2);

    // ---- prep (zero CNT + weight split + question path) ----
    k_prep<<<225, 512, 0, stream>>>(qe, fc0w, fc0b, fc1w, fc1b, W0, W1, W2, fc2w,
                                    WTH, WTL, CNT, QQ);
    // ---- CSR build ----
    k_hist<<<eb, 256, 0, stream>>>(ei, CNT, RANK, E);
    k_scan_a<<<sb, 512, 0, stream>>>(CNT, ROWPTR, BSUM, DINV, N);
    k_scan_c<<<sb, 512, 0, stream>>>(ROWPTR, BSUM, N, E, sb);
    k_fill_csr<<<eb, 256, 0, stream>>>(ei, ROWPTR, RANK, COL, E);

    // ---- layer 1 ----
    gemm_mf<0><<<gg, 128, 0, stream>>>(x, nullptr, nullptr, WTH, WTL, DINV, HS, N);
    k_gather<<<gat, 256, 0, stream>>>((const unsigned*)HS, ROWPTR, COL, DINV, b0,
                                      (unsigned*)GH, (unsigned*)GL, N);
    // ---- layer 2 ----
    gemm_mf<1><<<gg, 128, 0, stream>>>(nullptr, GH, GL, WTH + 16384, WTL + 16384, DINV, HS, N);
    k_gather<<<gat, 256, 0, stream>>>((const unsigned*)HS, ROWPTR, COL, DINV, b1,
                                      (unsigned*)GH, (unsigned*)GL, N);
    // ---- layer 3 ----
    gemm_mf<1><<<gg, 128, 0, stream>>>(nullptr, GH, GL, WTH + 32768, WTL + 32768, DINV, HS, N);
    k_gather<<<gat, 256, 0, stream>>>((const unsigned*)HS, ROWPTR, COL, DINV, b2,
                                      (unsigned*)GH, (unsigned*)GL, N);

    // ---- fused fc1 + fc2 -> d_out ----
    k_fc12<<<(N + 31) / 32, 128, 0, stream>>>(GH, GL, WTH + 49152, WTL + 49152,
                                              WTH + 65536, WTL + 65536,
                                              QQ, batch, fc2b, out, N);
}

// Round 9
// 333.696 us; speedup vs baseline: 1.5981x; 1.2237x over previous
//
#include <hip/hip_runtime.h>
#include <hip/hip_bf16.h>

#define N_NODES 50000
#define N_EDGES 800000
#define N_GRAPHS 64
#define LSTR 136

typedef __attribute__((ext_vector_type(4))) short s4v;
typedef __attribute__((ext_vector_type(8))) short s8v;
typedef __attribute__((ext_vector_type(16))) float f16v;

struct HL { short hi, lo; };

// round-to-nearest-even split of fp32 into bf16 hi + bf16 lo
__device__ inline HL bsplit(float f) {
    HL r;
    unsigned u = __float_as_uint(f);
    unsigned rh = (u + 0x7FFFu + ((u >> 16) & 1u)) >> 16;
    r.hi = (short)rh;
    float fh = __uint_as_float(rh << 16);
    float fl = f - fh;
    unsigned u2 = __float_as_uint(fl);
    unsigned rl = (u2 + 0x7FFFu + ((u2 >> 16) & 1u)) >> 16;
    r.lo = (short)rl;
    return r;
}

__device__ inline unsigned short f2bf(float f) {
    unsigned u = __float_as_uint(f);
    return (unsigned short)((u + 0x7FFFu + ((u >> 16) & 1u)) >> 16);
}

__device__ inline float bflo(unsigned u) { return __uint_as_float(u << 16); }
__device__ inline float bfhi(unsigned u) { return __uint_as_float(u & 0xFFFF0000u); }

// ---------------- degree / CSR ----------------

__global__ void k_hist(const int* __restrict__ ei, int* __restrict__ cnt,
                       int* __restrict__ rank, int E) {
    int e = blockIdx.x * 256 + threadIdx.x;
    if (e < E) rank[e] = atomicAdd(&cnt[ei[E + e]], 1);
}

// scan over PADDED counts (deg rounded up to multiple of 8); dinv from real deg
__global__ __launch_bounds__(512) void k_scan_a(const int* __restrict__ cnt,
                                                int* __restrict__ rowptr,
                                                int* __restrict__ bsum,
                                                float* __restrict__ dinv, int n) {
    __shared__ int s[512];
    int t = threadIdx.x;
    int i = blockIdx.x * 512 + t;
    int v = (i < n) ? cnt[i] : 0;
    if (i < n) dinv[i] = rsqrtf((float)(v + 1));
    int pv = (v + 7) & ~7;
    s[t] = pv;
    __syncthreads();
    for (int d = 1; d < 512; d <<= 1) {
        int x = (t >= d) ? s[t - d] : 0;
        __syncthreads();
        s[t] += x;
        __syncthreads();
    }
    if (i < n) rowptr[i] = s[t] - pv;
    if (t == 511) bsum[blockIdx.x] = s[511];
}

// merged scan_b+scan_c; also writes rowptr[n] = padded total
__global__ __launch_bounds__(512) void k_scan_c(int* __restrict__ rowptr,
                                                const int* __restrict__ bsum,
                                                int n, int nb) {
    __shared__ int sb[128];
    int t = threadIdx.x;
    if (t < 128) sb[t] = (t < nb) ? bsum[t] : 0;
    __syncthreads();
    for (int d = 1; d < 128; d <<= 1) {
        int x = 0;
        if (t < 128 && t >= d) x = sb[t - d];
        __syncthreads();
        if (t < 128) sb[t] += x;
        __syncthreads();
    }
    int add = (blockIdx.x > 0) ? sb[blockIdx.x - 1] : 0;
    int i = blockIdx.x * 512 + t;
    if (i < n) rowptr[i] += add;
    if (i == 0) rowptr[n] = sb[nb - 1];
}

// no atomic: position = rowptr[dst] + rank[e]; 16-bit indices
__global__ void k_fill_csr(const int* __restrict__ ei, const int* __restrict__ rowptr,
                           const int* __restrict__ rank,
                           unsigned short* __restrict__ colA, int E) {
    int e = blockIdx.x * 256 + threadIdx.x;
    if (e >= E) return;
    colA[rowptr[ei[E + e]] + rank[e]] = (unsigned short)ei[e];
}

// ---- prep: qq (0..63) | wsplit (64..199) | CNT zero + Hs pad row (200..224) | colA pad fill (225..505)
__global__ __launch_bounds__(512) void k_prep(const float* __restrict__ qe,
                                              const float* __restrict__ fc0w,
                                              const float* __restrict__ fc0b,
                                              const float* __restrict__ fc1w,
                                              const float* __restrict__ fc1b,
                                              const float* __restrict__ W0,
                                              const float* __restrict__ W1,
                                              const float* __restrict__ W2,
                                              const float* __restrict__ fc2w,
                                              short* __restrict__ WH,
                                              short* __restrict__ WL,
                                              int* __restrict__ cntz,
                                              unsigned* __restrict__ Hsd,
                                              unsigned short* __restrict__ colA,
                                              float* __restrict__ qq) {
    int b = blockIdx.x, tid = threadIdx.x;
    if (b >= 225) {                       // colA pad prefill: 1,150,016 ushorts as uint4
        int idx = (b - 225) * 512 + tid;
        if (idx < 143752) {
            uint4 p;
            p.x = p.y = p.z = p.w = 0xC350C350u;   // 50000 | 50000<<16
            ((uint4*)colA)[idx] = p;
        }
        return;
    }
    if (b >= 200) {                       // zero CNT (+ dummy Hs row on b==200)
        int idx = (b - 200) * 512 + tid;
        if (idx < 12504) ((int4*)cntz)[idx] = make_int4(0, 0, 0, 0);
        if (b == 200 && tid < 64) Hsd[(unsigned)N_NODES * 64u + tid] = 0u;
        return;
    }
    if (b >= 64) {                        // weight split: 136 blocks x 512 = 69632 exact
        int i = (b - 64) * 512 + tid;
        float val;
        int dst;
        if (i < 65536) {
            int mat = i >> 14, off = i & 16383;
            int k = off >> 7, n = off & 127;
            const float* src = (mat == 0) ? W0 : (mat == 1) ? W1 : (mat == 2) ? W2 : fc1w;
            val = src[k * 128 + n];
            dst = mat * 16384 + n * 128 + k;
        } else {
            int off = i - 65536;
            int k = off >> 5, n = off & 31;
            val = fc2w[k * 32 + n];
            dst = 65536 + n * 128 + k;
        }
        HL r = bsplit(val);
        WH[dst] = r.hi;
        WL[dst] = r.lo;
        return;
    }
    // question path, graph g = b
    __shared__ float qs[768];
    __shared__ float red[512];
    __shared__ float ql[128];
    const float* fc1bot = fc1w + 128 * 128;
    int g = b;
    for (int i = tid; i < 768; i += 512) qs[i] = qe[g * 768 + i];
    __syncthreads();
    int j = tid & 127, sl = tid >> 7;
    int kb = sl * 192;
    float a0 = 0, a1 = 0, a2 = 0, a3 = 0;
    for (int k = 0; k < 192; k += 4) {
        a0 += qs[kb + k + 0] * fc0w[(kb + k + 0) * 128 + j];
        a1 += qs[kb + k + 1] * fc0w[(kb + k + 1) * 128 + j];
        a2 += qs[kb + k + 2] * fc0w[(kb + k + 2) * 128 + j];
        a3 += qs[kb + k + 3] * fc0w[(kb + k + 3) * 128 + j];
    }
    red[tid] = (a0 + a1) + (a2 + a3);
    __syncthreads();
    if (tid < 128)
        ql[tid] = fmaxf(((red[tid] + red[tid + 128]) + (red[tid + 256] + red[tid + 384]))
                        + fc0b[tid], 0.f);
    __syncthreads();
    kb = sl * 32;
    float b0 = 0, b1 = 0;
    for (int k = 0; k < 32; k += 2) {
        b0 += ql[kb + k + 0] * fc1bot[(kb + k + 0) * 128 + j];
        b1 += ql[kb + k + 1] * fc1bot[(kb + k + 1) * 128 + j];
    }
    red[tid] = b0 + b1;
    __syncthreads();
    if (tid < 128)
        qq[g * 128 + tid] = ((red[tid] + red[tid + 128]) + (red[tid + 256] + red[tid + 384]))
                            + fc1b[tid];
}

// ---------------- CSR gather, scalar-indexed, tail-free (deg padded to 8) ----------------
// One wave per node; lane l handles features 2l,2l+1 (one dword of the bf16 row).
// 8 indices per uniform uint4 load of ushort colA; pad slots point at zero row N_NODES.
__global__ __launch_bounds__(256) void k_gather(const unsigned* __restrict__ Hs,
                                                const int* __restrict__ rowptr,
                                                const unsigned short* __restrict__ colA,
                                                const float* __restrict__ dinv,
                                                const float* __restrict__ bias,
                                                unsigned* __restrict__ GH, int n) {
    int node = __builtin_amdgcn_readfirstlane(blockIdx.x * 4 + (threadIdx.x >> 6));
    if (node >= n) return;
    int l = threadIdx.x & 63;
    int e0 = __builtin_amdgcn_readfirstlane(rowptr[node]);
    int e1 = __builtin_amdgcn_readfirstlane(rowptr[node + 1]);
    float a0 = 0.f, a1 = 0.f;
    for (int e = e0; e < e1; e += 8) {
        uint4 cw = *(const uint4*)(colA + e);     // uniform -> scalar load
        const unsigned* r0 = Hs + (cw.x & 0xFFFFu) * 64u;
        const unsigned* r1 = Hs + (cw.x >> 16) * 64u;
        const unsigned* r2 = Hs + (cw.y & 0xFFFFu) * 64u;
        const unsigned* r3 = Hs + (cw.y >> 16) * 64u;
        const unsigned* r4 = Hs + (cw.z & 0xFFFFu) * 64u;
        const unsigned* r5 = Hs + (cw.z >> 16) * 64u;
        const unsigned* r6 = Hs + (cw.w & 0xFFFFu) * 64u;
        const unsigned* r7 = Hs + (cw.w >> 16) * 64u;
        unsigned u0 = r0[l], u1 = r1[l], u2 = r2[l], u3 = r3[l];
        unsigned u4 = r4[l], u5 = r5[l], u6 = r6[l], u7 = r7[l];
        a0 += ((bflo(u0) + bflo(u1)) + (bflo(u2) + bflo(u3)))
            + ((bflo(u4) + bflo(u5)) + (bflo(u6) + bflo(u7)));
        a1 += ((bfhi(u0) + bfhi(u1)) + (bfhi(u2) + bfhi(u3)))
            + ((bfhi(u4) + bfhi(u5)) + (bfhi(u6) + bfhi(u7)));
    }
    float di = dinv[node];
    unsigned uh = Hs[(unsigned)node * 64u + l];
    float2 bb = ((const float2*)bias)[l];
    float o0 = fmaxf((a0 + bflo(uh)) * di + bb.x, 0.f);
    float o1 = fmaxf((a1 + bfhi(uh)) * di + bb.y, 0.f);
    GH[(unsigned)node * 64u + l] = (unsigned)f2bf(o0) | ((unsigned)f2bf(o1) << 16);
}

// ---------------- 2-term MFMA GEMM: Hs_bf16 = (A@W)*dinv[row] ----------------
// Single A-plane in LDS; W hi+lo fragments straight from global (L2-hot).
// SPLITIN 0: A fp32 -> bf16 on the fly     SPLITIN 1: A = GH bf16
template <int SPLITIN>
__global__ __launch_bounds__(128) void gemm_mf(const float* __restrict__ A32,
                                               const unsigned short* __restrict__ GHin,
                                               const short* __restrict__ WTh,
                                               const short* __restrict__ WTl,
                                               const float* __restrict__ dinv,
                                               unsigned short* __restrict__ oHs,
                                               int nrows) {
    __shared__ short Ah[32 * LSTR];
    const int tid = threadIdx.x;
    const int row0 = blockIdx.x * 32;

    if (SPLITIN == 0) {
        #pragma unroll
        for (int i = 0; i < 8; ++i) {
            int u = i * 128 + tid;
            int r = u >> 5, c4 = u & 31;
            int gr = row0 + r;
            float4 v = make_float4(0.f, 0.f, 0.f, 0.f);
            if (gr < nrows) v = ((const float4*)A32)[(size_t)gr * 32 + c4];
            s4v h4 = {(short)f2bf(v.x), (short)f2bf(v.y), (short)f2bf(v.z), (short)f2bf(v.w)};
            *(s4v*)&Ah[r * LSTR + c4 * 4] = h4;
        }
    } else {
        #pragma unroll
        for (int i = 0; i < 4; ++i) {
            int u = i * 128 + tid;
            int r = u >> 4, j = u & 15;
            int gr = row0 + r;
            s8v h8 = {};
            if (gr < nrows) h8 = *(const s8v*)&GHin[(size_t)gr * 128 + j * 8];
            *(s8v*)&Ah[r * LSTR + j * 8] = h8;
        }
    }
    __syncthreads();

    const int wv = tid >> 6, lane = tid & 63;
    const int m = lane & 31, half = lane >> 5;
    const int c0 = wv * 64 + m;
    f16v acc0 = {0.f}, acc1 = {0.f};
    #pragma unroll
    for (int ks = 0; ks < 8; ++ks) {
        int ko = ks * 16 + half * 8;
        s8v ah  = *(const s8v*)&Ah[m * LSTR + ko];
        s8v bh0 = *(const s8v*)&WTh[(size_t)c0 * 128 + ko];
        s8v bl0 = *(const s8v*)&WTl[(size_t)c0 * 128 + ko];
        s8v bh1 = *(const s8v*)&WTh[(size_t)(c0 + 32) * 128 + ko];
        s8v bl1 = *(const s8v*)&WTl[(size_t)(c0 + 32) * 128 + ko];
        acc0 = __builtin_amdgcn_mfma_f32_32x32x16_bf16(ah, bh0, acc0, 0, 0, 0);
        acc0 = __builtin_amdgcn_mfma_f32_32x32x16_bf16(ah, bl0, acc0, 0, 0, 0);
        acc1 = __builtin_amdgcn_mfma_f32_32x32x16_bf16(ah, bh1, acc1, 0, 0, 0);
        acc1 = __builtin_amdgcn_mfma_f32_32x32x16_bf16(ah, bl1, acc1, 0, 0, 0);
    }

    #pragma unroll
    for (int reg = 0; reg < 16; ++reg) {
        int rl = (reg & 3) + 8 * (reg >> 2) + 4 * half;
        int gr = row0 + rl;
        if (gr >= nrows) continue;
        float sc = dinv[gr];
        oHs[(size_t)gr * 128 + c0]      = f2bf(acc0[reg] * sc);
        oHs[(size_t)gr * 128 + c0 + 32] = f2bf(acc1[reg] * sc);
    }
}

// ---------------- fused fc1+fc2 -> d_out ----------------
__global__ __launch_bounds__(128) void k_fc12(const unsigned short* __restrict__ GHin,
                                              const short* __restrict__ W1h,
                                              const short* __restrict__ W1l,
                                              const short* __restrict__ W2h,
                                              const short* __restrict__ W2l,
                                              const float* __restrict__ qq,
                                              const int* __restrict__ batch,
                                              const float* __restrict__ bias,
                                              float* __restrict__ out, int nrows) {
    __shared__ short Ph[32 * LSTR], Pl[32 * LSTR];
    __shared__ float red[32 * 33];
    const int tid = threadIdx.x;
    const int row0 = blockIdx.x * 32;

    #pragma unroll
    for (int i = 0; i < 4; ++i) {              // A: single bf16 plane
        int u = i * 128 + tid;
        int r = u >> 4, j = u & 15;
        int gr = row0 + r;
        s8v h8 = {};
        if (gr < nrows) h8 = *(const s8v*)&GHin[(size_t)gr * 128 + j * 8];
        *(s8v*)&Ph[r * LSTR + j * 8] = h8;
    }
    __syncthreads();

    const int wv = tid >> 6, lane = tid & 63;
    const int m = lane & 31, half = lane >> 5;
    const int c0 = wv * 64 + m;
    f16v acc0 = {0.f}, acc1 = {0.f};
    #pragma unroll
    for (int ks = 0; ks < 8; ++ks) {
        int ko = ks * 16 + half * 8;
        s8v ah  = *(const s8v*)&Ph[m * LSTR + ko];
        s8v bh0 = *(const s8v*)&W1h[(size_t)c0 * 128 + ko];
        s8v bl0 = *(const s8v*)&W1l[(size_t)c0 * 128 + ko];
        s8v bh1 = *(const s8v*)&W1h[(size_t)(c0 + 32) * 128 + ko];
        s8v bl1 = *(const s8v*)&W1l[(size_t)(c0 + 32) * 128 + ko];
        acc0 = __builtin_amdgcn_mfma_f32_32x32x16_bf16(ah, bh0, acc0, 0, 0, 0);
        acc0 = __builtin_amdgcn_mfma_f32_32x32x16_bf16(ah, bl0, acc0, 0, 0, 0);
        acc1 = __builtin_amdgcn_mfma_f32_32x32x16_bf16(ah, bh1, acc1, 0, 0, 0);
        acc1 = __builtin_amdgcn_mfma_f32_32x32x16_bf16(ah, bl1, acc1, 0, 0, 0);
    }
    __syncthreads();                            // done reading Ph

    // epilogue: relu(+qq), split into P hi/lo planes in LDS
    #pragma unroll
    for (int reg = 0; reg < 16; ++reg) {
        int rl = (reg & 3) + 8 * (reg >> 2) + 4 * half;
        int gr = row0 + rl;
        int g = (gr < nrows) ? batch[gr] : 0;
        float q0 = qq[(size_t)g * 128 + c0];
        float q1 = qq[(size_t)g * 128 + c0 + 32];
        float v0 = fmaxf(acc0[reg] + q0, 0.f);
        float v1 = fmaxf(acc1[reg] + q1, 0.f);
        HL p0 = bsplit(v0), p1 = bsplit(v1);
        Ph[rl * LSTR + c0] = p0.hi;
        Pl[rl * LSTR + c0] = p0.lo;
        Ph[rl * LSTR + c0 + 32] = p1.hi;
        Pl[rl * LSTR + c0 + 32] = p1.lo;
    }
    __syncthreads();

    // stage 2: split-K across waves, 3-term (P hi+lo, W2 hi)
    f16v acc2 = {0.f};
    #pragma unroll
    for (int ks = 0; ks < 4; ++ks) {
        int ko = wv * 64 + ks * 16 + half * 8;
        s8v ah = *(const s8v*)&Ph[m * LSTR + ko];
        s8v al = *(const s8v*)&Pl[m * LSTR + ko];
        s8v bh = *(const s8v*)&W2h[(size_t)m * 128 + ko];
        s8v bl = *(const s8v*)&W2l[(size_t)m * 128 + ko];
        acc2 = __builtin_amdgcn_mfma_f32_32x32x16_bf16(ah, bh, acc2, 0, 0, 0);
        acc2 = __builtin_amdgcn_mfma_f32_32x32x16_bf16(ah, bl, acc2, 0, 0, 0);
        acc2 = __builtin_amdgcn_mfma_f32_32x32x16_bf16(al, bh, acc2, 0, 0, 0);
    }
    if (wv == 1) {
        #pragma unroll
        for (int reg = 0; reg < 16; ++reg) {
            int rl = (reg & 3) + 8 * (reg >> 2) + 4 * half;
            red[rl * 33 + m] = acc2[reg];
        }
    }
    __syncthreads();
    if (wv == 0) {
        #pragma unroll
        for (int reg = 0; reg < 16; ++reg) {
            int rl = (reg & 3) + 8 * (reg >> 2) + 4 * half;
            int gr = row0 + rl;
            if (gr < nrows)
                out[(size_t)gr * 32 + m] = acc2[reg] + red[rl * 33 + m] + bias[m];
        }
    }
}

// ---------------- launch ----------------

extern "C" void kernel_launch(void* const* d_in, const int* in_sizes, int n_in,
                              void* d_out, int out_size, void* d_ws, size_t ws_size,
                              hipStream_t stream) {
    const float* x    = (const float*)d_in[0];
    const int*   ei   = (const int*)d_in[1];
    const int*   batch= (const int*)d_in[2];
    const float* qe   = (const float*)d_in[3];
    const float* W0   = (const float*)d_in[4];
    const float* b0   = (const float*)d_in[5];
    const float* W1   = (const float*)d_in[6];
    const float* b1   = (const float*)d_in[7];
    const float* W2   = (const float*)d_in[8];
    const float* b2   = (const float*)d_in[9];
    const float* fc0w = (const float*)d_in[10];
    const float* fc0b = (const float*)d_in[11];
    const float* fc1w = (const float*)d_in[12];
    const float* fc1b = (const float*)d_in[13];
    const float* fc2w = (const float*)d_in[14];
    const float* fc2b = (const float*)d_in[15];
    float* out = (float*)d_out;

    float* WS = (float*)d_ws;
    unsigned short* HS = (unsigned short*)WS;                 // bf16 [50001,128] (+pad row)
    unsigned short* GH = (unsigned short*)(WS + 3200064);     // bf16 [50000,128]
    float* DINV = WS + 6400064;              // [50016]
    float* QQ   = WS + 6450080;              // [8192]
    int*   CNT  = (int*)(WS + 6458272);      // [50016]
    int*   ROWPTR = (int*)(WS + 6508288);    // [50016]
    int*   RANK = (int*)(WS + 6558304);      // [800000]
    unsigned short* COL = (unsigned short*)(WS + 7358304);    // [1150016] ushort
    int*   BSUM = (int*)(WS + 7933312);      // [128]
    short* WTH  = (short*)(WS + 7933440);    // [69632]
    short* WTL  = WTH + 69632;               // [69632]

    const int N = N_NODES, E = N_EDGES;
    const int eb = (E + 255) / 256;
    const int sb = (N + 511) / 512;          // 98
    const int gg = (N + 31) / 32;            // 1563
    const int gat = (N + 3) / 4;             // 12500

    // ---- prep (qq + wsplit + CNT zero + Hs pad row + colA pad prefill) ----
    k_prep<<<506, 512, 0, stream>>>(qe, fc0w, fc0b, fc1w, fc1b, W0, W1, W2, fc2w,
                                    WTH, WTL, CNT, (unsigned*)HS, COL, QQ);
    // ---- CSR build (padded) ----
    k_hist<<<eb, 256, 0, stream>>>(ei, CNT, RANK, E);
    k_scan_a<<<sb, 512, 0, stream>>>(CNT, ROWPTR, BSUM, DINV, N);
    k_scan_c<<<sb, 512, 0, stream>>>(ROWPTR, BSUM, N, sb);
    k_fill_csr<<<eb, 256, 0, stream>>>(ei, ROWPTR, RANK, COL, E);

    // ---- layer 1 ----
    gemm_mf<0><<<gg, 128, 0, stream>>>(x, nullptr, WTH, WTL, DINV, HS, N);
    k_gather<<<gat, 256, 0, stream>>>((const unsigned*)HS, ROWPTR, COL, DINV, b0,
                                      (unsigned*)GH, N);
    // ---- layer 2 ----
    gemm_mf<1><<<gg, 128, 0, stream>>>(nullptr, GH, WTH + 16384, WTL + 16384, DINV, HS, N);
    k_gather<<<gat, 256, 0, stream>>>((const unsigned*)HS, ROWPTR, COL, DINV, b1,
                                      (unsigned*)GH, N);
    // ---- layer 3 ----
    gemm_mf<1><<<gg, 128, 0, stream>>>(nullptr, GH, WTH + 32768, WTL + 32768, DINV, HS, N);
    k_gather<<<gat, 256, 0, stream>>>((const unsigned*)HS, ROWPTR, COL, DINV, b2,
                                      (unsigned*)GH, N);

    // ---- fused fc1 + fc2 -> d_out ----
    k_fc12<<<gg, 128, 0, stream>>>(GH, WTH + 49152, WTL + 49152,
                                   WTH + 65536, WTL + 65536,
                                   QQ, batch, fc2b, out, N);
}

// Round 10
// 323.132 us; speedup vs baseline: 1.6503x; 1.0327x over previous
//
#include <hip/hip_runtime.h>
#include <hip/hip_bf16.h>

#define N_NODES 50000
#define N_EDGES 800000
#define N_GRAPHS 64
#define LSTR 136

typedef __attribute__((ext_vector_type(4))) short s4v;
typedef __attribute__((ext_vector_type(8))) short s8v;
typedef __attribute__((ext_vector_type(16))) float f16v;

struct HL { short hi, lo; };

__device__ inline HL bsplit(float f) {
    HL r;
    unsigned u = __float_as_uint(f);
    unsigned rh = (u + 0x7FFFu + ((u >> 16) & 1u)) >> 16;
    r.hi = (short)rh;
    float fh = __uint_as_float(rh << 16);
    float fl = f - fh;
    unsigned u2 = __float_as_uint(fl);
    unsigned rl = (u2 + 0x7FFFu + ((u2 >> 16) & 1u)) >> 16;
    r.lo = (short)rl;
    return r;
}

__device__ inline unsigned short f2bf(float f) {
    unsigned u = __float_as_uint(f);
    return (unsigned short)((u + 0x7FFFu + ((u >> 16) & 1u)) >> 16);
}

__device__ inline float bflo(unsigned u) { return __uint_as_float(u << 16); }
__device__ inline float bfhi(unsigned u) { return __uint_as_float(u & 0xFFFF0000u); }

// ---------------- degree / CSR ----------------

__global__ void k_hist(const int* __restrict__ ei, int* __restrict__ cnt,
                       int* __restrict__ rank, int E) {
    int e = blockIdx.x * 256 + threadIdx.x;
    if (e < E) rank[e] = atomicAdd(&cnt[ei[E + e]], 1);
}

// scan over PADDED counts (deg rounded up to multiple of 8); dinv from real deg
__global__ __launch_bounds__(512) void k_scan_a(const int* __restrict__ cnt,
                                                int* __restrict__ rowptr,
                                                int* __restrict__ bsum,
                                                float* __restrict__ dinv, int n) {
    __shared__ int s[512];
    int t = threadIdx.x;
    int i = blockIdx.x * 512 + t;
    int v = (i < n) ? cnt[i] : 0;
    if (i < n) dinv[i] = rsqrtf((float)(v + 1));
    int pv = (v + 7) & ~7;
    s[t] = pv;
    __syncthreads();
    for (int d = 1; d < 512; d <<= 1) {
        int x = (t >= d) ? s[t - d] : 0;
        __syncthreads();
        s[t] += x;
        __syncthreads();
    }
    if (i < n) rowptr[i] = s[t] - pv;
    if (t == 511) bsum[blockIdx.x] = s[511];
}

__global__ __launch_bounds__(512) void k_scan_c(int* __restrict__ rowptr,
                                                const int* __restrict__ bsum,
                                                int n, int nb) {
    __shared__ int sb[128];
    int t = threadIdx.x;
    if (t < 128) sb[t] = (t < nb) ? bsum[t] : 0;
    __syncthreads();
    for (int d = 1; d < 128; d <<= 1) {
        int x = 0;
        if (t < 128 && t >= d) x = sb[t - d];
        __syncthreads();
        if (t < 128) sb[t] += x;
        __syncthreads();
    }
    int add = (blockIdx.x > 0) ? sb[blockIdx.x - 1] : 0;
    int i = blockIdx.x * 512 + t;
    if (i < n) rowptr[i] += add;
    if (i == 0) rowptr[n] = sb[nb - 1];
}

__global__ void k_fill_csr(const int* __restrict__ ei, const int* __restrict__ rowptr,
                           const int* __restrict__ rank,
                           unsigned short* __restrict__ colA, int E) {
    int e = blockIdx.x * 256 + threadIdx.x;
    if (e >= E) return;
    colA[rowptr[ei[E + e]] + rank[e]] = (unsigned short)ei[e];
}

// ---- prep: qq (0..63) | wsplit (64..199) | CNT zero + dummy rows (200..224) | colA pad fill (225..505)
__global__ __launch_bounds__(512) void k_prep(const float* __restrict__ qe,
                                              const float* __restrict__ fc0w,
                                              const float* __restrict__ fc0b,
                                              const float* __restrict__ fc1w,
                                              const float* __restrict__ fc1b,
                                              const float* __restrict__ W0,
                                              const float* __restrict__ W1,
                                              const float* __restrict__ W2,
                                              const float* __restrict__ fc2w,
                                              short* __restrict__ WH,
                                              short* __restrict__ WL,
                                              int* __restrict__ cntz,
                                              unsigned* __restrict__ Hsd,
                                              unsigned* __restrict__ Hsd2,
                                              unsigned short* __restrict__ colA,
                                              float* __restrict__ qq) {
    int b = blockIdx.x, tid = threadIdx.x;
    if (b >= 225) {                       // colA pad prefill: 1,150,016 ushorts as uint4
        int idx = (b - 225) * 512 + tid;
        if (idx < 143752) {
            uint4 p;
            p.x = p.y = p.z = p.w = 0xC350C350u;   // 50000 | 50000<<16
            ((uint4*)colA)[idx] = p;
        }
        return;
    }
    if (b >= 200) {                       // zero CNT (+ dummy Hs rows on b==200)
        int idx = (b - 200) * 512 + tid;
        if (idx < 12504) ((int4*)cntz)[idx] = make_int4(0, 0, 0, 0);
        if (b == 200 && tid < 64) {
            Hsd[(unsigned)N_NODES * 64u + tid] = 0u;
            Hsd2[(unsigned)N_NODES * 64u + tid] = 0u;
        }
        return;
    }
    if (b >= 64) {                        // weight split: 136 blocks x 512 = 69632 exact
        int i = (b - 64) * 512 + tid;
        float val;
        int dst;
        if (i < 65536) {
            int mat = i >> 14, off = i & 16383;
            int k = off >> 7, n = off & 127;
            const float* src = (mat == 0) ? W0 : (mat == 1) ? W1 : (mat == 2) ? W2 : fc1w;
            val = src[k * 128 + n];
            dst = mat * 16384 + n * 128 + k;
        } else {
            int off = i - 65536;
            int k = off >> 5, n = off & 31;
            val = fc2w[k * 32 + n];
            dst = 65536 + n * 128 + k;
        }
        HL r = bsplit(val);
        WH[dst] = r.hi;
        WL[dst] = r.lo;
        return;
    }
    // question path, graph g = b
    __shared__ float qs[768];
    __shared__ float red[512];
    __shared__ float ql[128];
    const float* fc1bot = fc1w + 128 * 128;
    int g = b;
    for (int i = tid; i < 768; i += 512) qs[i] = qe[g * 768 + i];
    __syncthreads();
    int j = tid & 127, sl = tid >> 7;
    int kb = sl * 192;
    float a0 = 0, a1 = 0, a2 = 0, a3 = 0;
    for (int k = 0; k < 192; k += 4) {
        a0 += qs[kb + k + 0] * fc0w[(kb + k + 0) * 128 + j];
        a1 += qs[kb + k + 1] * fc0w[(kb + k + 1) * 128 + j];
        a2 += qs[kb + k + 2] * fc0w[(kb + k + 2) * 128 + j];
        a3 += qs[kb + k + 3] * fc0w[(kb + k + 3) * 128 + j];
    }
    red[tid] = (a0 + a1) + (a2 + a3);
    __syncthreads();
    if (tid < 128)
        ql[tid] = fmaxf(((red[tid] + red[tid + 128]) + (red[tid + 256] + red[tid + 384]))
                        + fc0b[tid], 0.f);
    __syncthreads();
    kb = sl * 32;
    float b0 = 0, b1 = 0;
    for (int k = 0; k < 32; k += 2) {
        b0 += ql[kb + k + 0] * fc1bot[(kb + k + 0) * 128 + j];
        b1 += ql[kb + k + 1] * fc1bot[(kb + k + 1) * 128 + j];
    }
    red[tid] = b0 + b1;
    __syncthreads();
    if (tid < 128)
        qq[g * 128 + tid] = ((red[tid] + red[tid + 128]) + (red[tid + 256] + red[tid + 384]))
                            + fc1b[tid];
}

// ---------------- layer-1 GEMM: Hs_bf16 = (x@W0)*dinv  (A fp32 -> bf16) ----------------
__global__ __launch_bounds__(128) void gemm_mf(const float* __restrict__ A32,
                                               const short* __restrict__ WTh,
                                               const short* __restrict__ WTl,
                                               const float* __restrict__ dinv,
                                               unsigned short* __restrict__ oHs,
                                               int nrows) {
    __shared__ short Ah[32 * LSTR];
    const int tid = threadIdx.x;
    const int row0 = blockIdx.x * 32;

    #pragma unroll
    for (int i = 0; i < 8; ++i) {
        int u = i * 128 + tid;
        int r = u >> 5, c4 = u & 31;
        int gr = row0 + r;
        float4 v = make_float4(0.f, 0.f, 0.f, 0.f);
        if (gr < nrows) v = ((const float4*)A32)[(size_t)gr * 32 + c4];
        s4v h4 = {(short)f2bf(v.x), (short)f2bf(v.y), (short)f2bf(v.z), (short)f2bf(v.w)};
        *(s4v*)&Ah[r * LSTR + c4 * 4] = h4;
    }
    __syncthreads();

    const int wv = tid >> 6, lane = tid & 63;
    const int m = lane & 31, half = lane >> 5;
    const int c0 = wv * 64 + m;
    f16v acc0 = {0.f}, acc1 = {0.f};
    #pragma unroll
    for (int ks = 0; ks < 8; ++ks) {
        int ko = ks * 16 + half * 8;
        s8v ah  = *(const s8v*)&Ah[m * LSTR + ko];
        s8v bh0 = *(const s8v*)&WTh[(size_t)c0 * 128 + ko];
        s8v bl0 = *(const s8v*)&WTl[(size_t)c0 * 128 + ko];
        s8v bh1 = *(const s8v*)&WTh[(size_t)(c0 + 32) * 128 + ko];
        s8v bl1 = *(const s8v*)&WTl[(size_t)(c0 + 32) * 128 + ko];
        acc0 = __builtin_amdgcn_mfma_f32_32x32x16_bf16(ah, bh0, acc0, 0, 0, 0);
        acc0 = __builtin_amdgcn_mfma_f32_32x32x16_bf16(ah, bl0, acc0, 0, 0, 0);
        acc1 = __builtin_amdgcn_mfma_f32_32x32x16_bf16(ah, bh1, acc1, 0, 0, 0);
        acc1 = __builtin_amdgcn_mfma_f32_32x32x16_bf16(ah, bl1, acc1, 0, 0, 0);
    }

    #pragma unroll
    for (int reg = 0; reg < 16; ++reg) {
        int rl = (reg & 3) + 8 * (reg >> 2) + 4 * half;
        int gr = row0 + rl;
        if (gr >= nrows) continue;
        float sc = dinv[gr];
        oHs[(size_t)gr * 128 + c0]      = f2bf(acc0[reg] * sc);
        oHs[(size_t)gr * 128 + c0 + 32] = f2bf(acc1[reg] * sc);
    }
}

// ---------------- fused gather + GEMM ----------------
// 256 thr (4 waves), 32 rows/block. Phase 1: each wave gathers 8 nodes into the
// LDS A-tile (scalar-indexed, tail-free). Phase 2: 32x128 MFMA, W from global (L2).
// FC=0: oHs = (G@W)*dinv        FC=1: fc1(relu,+qq) then fc2 -> out
template <int FC>
__global__ __launch_bounds__(256) void k_gg(const unsigned* __restrict__ Hs,
                                            const int* __restrict__ rowptr,
                                            const unsigned short* __restrict__ colA,
                                            const float* __restrict__ dinv,
                                            const float* __restrict__ bias,
                                            const short* __restrict__ WTh,
                                            const short* __restrict__ WTl,
                                            const short* __restrict__ W2h,
                                            const short* __restrict__ W2l,
                                            const float* __restrict__ qq,
                                            const int* __restrict__ batch,
                                            const float* __restrict__ fc2b,
                                            unsigned short* __restrict__ oHs,
                                            float* __restrict__ out,
                                            int n) {
    __shared__ short Ah[32 * LSTR];
    __shared__ short Pl[FC ? 32 * LSTR : 1];
    __shared__ float red[FC ? 3 * 32 * 33 : 1];
    const int tid = threadIdx.x;
    const int row0 = blockIdx.x * 32;
    const int wv = tid >> 6, l = tid & 63;
    const int m = l & 31, half = l >> 5;

    const float2 bb = ((const float2*)bias)[l];
    for (int i = 0; i < 8; ++i) {              // gather 8 nodes per wave
        int r = wv * 8 + i;
        int node = row0 + r;
        unsigned pack = 0;
        if (node < n) {
            int e0 = __builtin_amdgcn_readfirstlane(rowptr[node]);
            int e1 = __builtin_amdgcn_readfirstlane(rowptr[node + 1]);
            float a0 = 0.f, a1 = 0.f;
            for (int e = e0; e < e1; e += 8) {
                uint4 cw = *(const uint4*)(colA + e);     // uniform -> scalar load
                unsigned u0 = Hs[(cw.x & 0xFFFFu) * 64u + l];
                unsigned u1 = Hs[(cw.x >> 16) * 64u + l];
                unsigned u2 = Hs[(cw.y & 0xFFFFu) * 64u + l];
                unsigned u3 = Hs[(cw.y >> 16) * 64u + l];
                unsigned u4 = Hs[(cw.z & 0xFFFFu) * 64u + l];
                unsigned u5 = Hs[(cw.z >> 16) * 64u + l];
                unsigned u6 = Hs[(cw.w & 0xFFFFu) * 64u + l];
                unsigned u7 = Hs[(cw.w >> 16) * 64u + l];
                a0 += ((bflo(u0) + bflo(u1)) + (bflo(u2) + bflo(u3)))
                    + ((bflo(u4) + bflo(u5)) + (bflo(u6) + bflo(u7)));
                a1 += ((bfhi(u0) + bfhi(u1)) + (bfhi(u2) + bfhi(u3)))
                    + ((bfhi(u4) + bfhi(u5)) + (bfhi(u6) + bfhi(u7)));
            }
            float di = dinv[node];
            unsigned uh = Hs[(unsigned)node * 64u + l];
            float o0 = fmaxf((a0 + bflo(uh)) * di + bb.x, 0.f);
            float o1 = fmaxf((a1 + bfhi(uh)) * di + bb.y, 0.f);
            pack = (unsigned)f2bf(o0) | ((unsigned)f2bf(o1) << 16);
        }
        ((unsigned*)Ah)[r * 68 + l] = pack;    // row r, dword l (LSTR/2 = 68)
    }
    __syncthreads();

    const int c0 = wv * 32 + m;                 // each wave: one 32-col block
    f16v acc = {0.f};
    #pragma unroll
    for (int ks = 0; ks < 8; ++ks) {
        int ko = ks * 16 + half * 8;
        s8v ah = *(const s8v*)&Ah[m * LSTR + ko];
        s8v bh = *(const s8v*)&WTh[(size_t)c0 * 128 + ko];
        s8v bl = *(const s8v*)&WTl[(size_t)c0 * 128 + ko];
        acc = __builtin_amdgcn_mfma_f32_32x32x16_bf16(ah, bh, acc, 0, 0, 0);
        acc = __builtin_amdgcn_mfma_f32_32x32x16_bf16(ah, bl, acc, 0, 0, 0);
    }

    if (FC == 0) {
        #pragma unroll
        for (int reg = 0; reg < 16; ++reg) {
            int rl = (reg & 3) + 8 * (reg >> 2) + 4 * half;
            int gr = row0 + rl;
            if (gr >= n) continue;
            oHs[(size_t)gr * 128 + c0] = f2bf(acc[reg] * dinv[gr]);
        }
    } else {
        __syncthreads();                        // all waves done reading Ah
        #pragma unroll
        for (int reg = 0; reg < 16; ++reg) {    // relu(+qq), split into Ah/Pl planes
            int rl = (reg & 3) + 8 * (reg >> 2) + 4 * half;
            int gr = row0 + rl;
            int g = (gr < n) ? batch[gr] : 0;
            float v = fmaxf(acc[reg] + qq[(size_t)g * 128 + c0], 0.f);
            HL p = bsplit(v);
            Ah[rl * LSTR + c0] = p.hi;
            Pl[rl * LSTR + c0] = p.lo;
        }
        __syncthreads();
        f16v acc2 = {0.f};                      // fc2, split-K across 4 waves
        #pragma unroll
        for (int ks = 0; ks < 2; ++ks) {
            int ko = wv * 32 + ks * 16 + half * 8;
            s8v ah = *(const s8v*)&Ah[m * LSTR + ko];
            s8v al = *(const s8v*)&Pl[m * LSTR + ko];
            s8v bh = *(const s8v*)&W2h[(size_t)m * 128 + ko];
            s8v bl = *(const s8v*)&W2l[(size_t)m * 128 + ko];
            acc2 = __builtin_amdgcn_mfma_f32_32x32x16_bf16(ah, bh, acc2, 0, 0, 0);
            acc2 = __builtin_amdgcn_mfma_f32_32x32x16_bf16(ah, bl, acc2, 0, 0, 0);
            acc2 = __builtin_amdgcn_mfma_f32_32x32x16_bf16(al, bh, acc2, 0, 0, 0);
        }
        if (wv > 0) {
            #pragma unroll
            for (int reg = 0; reg < 16; ++reg) {
                int rl = (reg & 3) + 8 * (reg >> 2) + 4 * half;
                red[(wv - 1) * 1056 + rl * 33 + m] = acc2[reg];
            }
        }
        __syncthreads();
        if (wv == 0) {
            #pragma unroll
            for (int reg = 0; reg < 16; ++reg) {
                int rl = (reg & 3) + 8 * (reg >> 2) + 4 * half;
                int gr = row0 + rl;
                if (gr < n)
                    out[(size_t)gr * 32 + m] = acc2[reg]
                        + (red[rl * 33 + m] + red[1056 + rl * 33 + m])
                        + red[2112 + rl * 33 + m] + fc2b[m];
            }
        }
    }
}

// ---------------- launch ----------------

extern "C" void kernel_launch(void* const* d_in, const int* in_sizes, int n_in,
                              void* d_out, int out_size, void* d_ws, size_t ws_size,
                              hipStream_t stream) {
    const float* x    = (const float*)d_in[0];
    const int*   ei   = (const int*)d_in[1];
    const int*   batch= (const int*)d_in[2];
    const float* qe   = (const float*)d_in[3];
    const float* W0   = (const float*)d_in[4];
    const float* b0   = (const float*)d_in[5];
    const float* W1   = (const float*)d_in[6];
    const float* b1   = (const float*)d_in[7];
    const float* W2   = (const float*)d_in[8];
    const float* b2   = (const float*)d_in[9];
    const float* fc0w = (const float*)d_in[10];
    const float* fc0b = (const float*)d_in[11];
    const float* fc1w = (const float*)d_in[12];
    const float* fc1b = (const float*)d_in[13];
    const float* fc2w = (const float*)d_in[14];
    const float* fc2b = (const float*)d_in[15];
    float* out = (float*)d_out;

    float* WS = (float*)d_ws;
    unsigned short* HS  = (unsigned short*)WS;                // bf16 [50001,128]
    unsigned short* HS2 = (unsigned short*)(WS + 3200064);    // bf16 [50001,128]
    float* DINV = WS + 6400128;              // [50016]
    float* QQ   = WS + 6450144;              // [8192]
    int*   CNT  = (int*)(WS + 6458336);      // [50016]
    int*   ROWPTR = (int*)(WS + 6508352);    // [50016]
    int*   RANK = (int*)(WS + 6558368);      // [800000]
    unsigned short* COL = (unsigned short*)(WS + 7358368);    // [1150016] ushort
    int*   BSUM = (int*)(WS + 7933376);      // [128]
    short* WTH  = (short*)(WS + 7933504);    // [69632]
    short* WTL  = WTH + 69632;               // [69632]

    const int N = N_NODES, E = N_EDGES;
    const int eb = (E + 255) / 256;
    const int sb = (N + 511) / 512;          // 98
    const int gg = (N + 31) / 32;            // 1563

    // ---- prep (qq + wsplit + CNT zero + dummy rows + colA pad prefill) ----
    k_prep<<<506, 512, 0, stream>>>(qe, fc0w, fc0b, fc1w, fc1b, W0, W1, W2, fc2w,
                                    WTH, WTL, CNT, (unsigned*)HS, (unsigned*)HS2, COL, QQ);
    // ---- CSR build (padded, atomic-free fill) ----
    k_hist<<<eb, 256, 0, stream>>>(ei, CNT, RANK, E);
    k_scan_a<<<sb, 512, 0, stream>>>(CNT, ROWPTR, BSUM, DINV, N);
    k_scan_c<<<sb, 512, 0, stream>>>(ROWPTR, BSUM, N, sb);
    k_fill_csr<<<eb, 256, 0, stream>>>(ei, ROWPTR, RANK, COL, E);

    // ---- layer 1 GEMM: x@W0 -> HS ----
    gemm_mf<<<gg, 128, 0, stream>>>(x, WTH, WTL, DINV, HS, N);
    // ---- layer 2: gather(HS,b0) + @W1 -> HS2 ----
    k_gg<0><<<gg, 256, 0, stream>>>((const unsigned*)HS, ROWPTR, COL, DINV, b0,
                                    WTH + 16384, WTL + 16384, nullptr, nullptr,
                                    nullptr, nullptr, nullptr, HS2, nullptr, N);
    // ---- layer 3: gather(HS2,b1) + @W2 -> HS ----
    k_gg<0><<<gg, 256, 0, stream>>>((const unsigned*)HS2, ROWPTR, COL, DINV, b1,
                                    WTH + 32768, WTL + 32768, nullptr, nullptr,
                                    nullptr, nullptr, nullptr, HS, nullptr, N);
    // ---- final: gather(HS,b2) + fc1(+qq,relu) + fc2 -> d_out ----
    k_gg<1><<<gg, 256, 0, stream>>>((const unsigned*)HS, ROWPTR, COL, DINV, b2,
                                    WTH + 49152, WTL + 49152, WTH + 65536, WTL + 65536,
                                    QQ, batch, fc2b, nullptr, out, N);
}